// Round 1
// baseline (370.099 us; speedup 1.0000x reference)
//
#include <hip/hip_runtime.h>
#include <cmath>

// GPT2QuantAttention on MI355X (gfx950).
// B=4 S=1024 D=1024 H=16 HD=64, 8-bit per-tensor symmetric fake-quant.
//
// Pipeline (all on `stream`):
//   1. absmax_partial x5 (hidden, Wq, Wk, Wv, Wo)  -> partials
//   2. finalize_scales (scale = max(absmax/127, 1e-8))
//   3. quantize x5 -> int8 (rintf = round-half-even, IEEE div: matches jnp)
//   4. gemm_i8<0>: int8 MFMA (exact), epilogue writes Q,K as bf16 hi/lo
//      [B,H,S,HD] and V as bf16 hi/lo TRANSPOSED [B,H,HD,S] (PV B-operand)
//   5. attn_kernel: flash attention, hi/lo-split bf16 MFMA (3 passes)
//      => fp32-grade accuracy at MFMA speed; online softmax in fp32
//   6. absmax/finalize/quantize attn -> int8
//   7. gemm_i8<1>: output projection -> d_out fp32
//
// ws map (bytes, total ~72 MiB + 2KB):
//   [0,4M)    xi int8 (also reused as ai int8 for the output GEMM)
//   [4M,7M)   wqkv int8 (Wq|Wk|Wv stacked rows)
//   [7M,8M)   wo int8
//   [8M..56M) Qhi Qlo Khi Klo VThi VTlo (8M each, bf16)
//   [56M,72M) attn fp32 [4096,1024]
//   [72M+..)  partials[6][64], scales[6]

using f32x4 = __attribute__((ext_vector_type(4))) float;
using i32x4 = __attribute__((ext_vector_type(4))) int;
using s16x8 = __attribute__((ext_vector_type(8))) short;

#define DI __device__ __forceinline__

DI unsigned short f2bf(float x) {  // fp32 -> bf16, round-to-nearest-even
  unsigned u = __float_as_uint(x);
  return (unsigned short)((u + 0x7FFFu + ((u >> 16) & 1u)) >> 16);
}
DI float bf2f(unsigned short h) { return __uint_as_float(((unsigned)h) << 16); }

DI f32x4 mfma_bf16(s16x8 a, s16x8 b, f32x4 c) {
  return __builtin_amdgcn_mfma_f32_16x16x32_bf16(a, b, c, 0, 0, 0);
}
DI i32x4 mfma_i8(i32x4 a, i32x4 b, i32x4 c) {
  return __builtin_amdgcn_mfma_i32_16x16x64_i8(a, b, c, 0, 0, 0);
}

// global->LDS direct copy, 16B per lane. LDS dst = wave-uniform base + lane*16.
// Pointer->int->AS-pointer round trip is the CK-proven pattern.
#define GLD16(gp, sp)                                                        \
  __builtin_amdgcn_global_load_lds(                                          \
      (__attribute__((address_space(1))) void*)(unsigned long long)(gp),     \
      (__attribute__((address_space(3))) void*)(unsigned long long)(sp),     \
      16, 0, 0)

// ---------------------------------------------------------------- reductions
__global__ __launch_bounds__(256) void absmax_partial(
    const float* __restrict__ x, int n4, float* __restrict__ out) {
  float m = 0.f;
  const int stride = gridDim.x * blockDim.x;
  for (int i = blockIdx.x * blockDim.x + threadIdx.x; i < n4; i += stride) {
    f32x4 v = ((const f32x4*)x)[i];
    m = fmaxf(m, fmaxf(fmaxf(fabsf(v[0]), fabsf(v[1])),
                       fmaxf(fabsf(v[2]), fabsf(v[3]))));
  }
#pragma unroll
  for (int s = 1; s < 64; s <<= 1) m = fmaxf(m, __shfl_xor(m, s, 64));
  __shared__ float sm[4];
  if ((threadIdx.x & 63) == 0) sm[threadIdx.x >> 6] = m;
  __syncthreads();
  if (threadIdx.x == 0)
    out[blockIdx.x] = fmaxf(fmaxf(sm[0], sm[1]), fmaxf(sm[2], sm[3]));
}

__global__ __launch_bounds__(320) void finalize_scales(
    const float* __restrict__ partials, float* __restrict__ scales, int ntens) {
  int wv = threadIdx.x >> 6, l = threadIdx.x & 63;
  if (wv < ntens) {
    float m = partials[wv * 64 + l];
#pragma unroll
    for (int s = 1; s < 64; s <<= 1) m = fmaxf(m, __shfl_xor(m, s, 64));
    if (l == 0) scales[wv] = fmaxf(m / 127.0f, 1e-8f);
  }
}

__global__ __launch_bounds__(256) void quantize_kernel(
    const float* __restrict__ x, signed char* __restrict__ q,
    const float* __restrict__ scale_p, int n4) {
  const float s = scale_p[0];
  const int stride = gridDim.x * blockDim.x;
  for (int i = blockIdx.x * blockDim.x + threadIdx.x; i < n4; i += stride) {
    f32x4 v = ((const f32x4*)x)[i];
    int packed = 0;
#pragma unroll
    for (int j = 0; j < 4; j++) {
      float r = rintf(v[j] / s);           // IEEE div + RNE: matches jnp
      r = fminf(fmaxf(r, -127.f), 127.f);
      packed |= (((int)r) & 0xFF) << (8 * j);
    }
    ((int*)q)[i] = packed;
  }
}

// ------------------------------------------------------------------ i8 GEMM
// C[m,n] = sum_k A[m,k]*Bw[n,k]  (both K-major), 128x128 tile, 4 waves (2x2),
// K-step 64 B: LDS fragment-major [4 kslot][128 row][16B] -> ds_read_b128
// is 2-way bank-aliased (free). One mfma_i32_16x16x64_i8 eats the K-step.
template <int EPI>
__global__ __launch_bounds__(256) void gemm_i8_kernel(
    const signed char* __restrict__ A, const signed char* __restrict__ Bw,
    const float* __restrict__ scales, const float* __restrict__ b0,
    const float* __restrict__ b1, const float* __restrict__ b2,
    unsigned short* __restrict__ q_hi, unsigned short* __restrict__ q_lo,
    unsigned short* __restrict__ k_hi, unsigned short* __restrict__ k_lo,
    unsigned short* __restrict__ vt_hi, unsigned short* __restrict__ vt_lo,
    float* __restrict__ out) {
  __shared__ __align__(16) signed char sA[8192];
  __shared__ __align__(16) signed char sB[8192];
  const int tid = threadIdx.x, w = tid >> 6, l = tid & 63;
  const int m0 = blockIdx.y * 128, n0 = blockIdx.x * 128;
  const int wm = w >> 1, wn = w & 1;
  const i32x4 zi = {0, 0, 0, 0};
  i32x4 acc[4][4];
#pragma unroll
  for (int r = 0; r < 4; r++)
#pragma unroll
    for (int c = 0; c < 4; c++) acc[r][c] = zi;

  for (int kb = 0; kb < 1024; kb += 64) {
    __syncthreads();
#pragma unroll
    for (int i = 0; i < 2; i++) {
      int u = i * 4 + w;                       // wave-uniform
      int slot = u >> 1, row = (u & 1) * 64 + l;
      GLD16(A + (size_t)(m0 + row) * 1024 + kb + slot * 16, sA + u * 1024);
      GLD16(Bw + (size_t)(n0 + row) * 1024 + kb + slot * 16, sB + u * 1024);
    }
    __syncthreads();
    i32x4 af[4], bf[4];
#pragma unroll
    for (int r = 0; r < 4; r++)
      af[r] = *(const i32x4*)(sA + ((l >> 4) * 2048 +
                                    (wm * 64 + r * 16 + (l & 15)) * 16));
#pragma unroll
    for (int c = 0; c < 4; c++)
      bf[c] = *(const i32x4*)(sB + ((l >> 4) * 2048 +
                                    (wn * 64 + c * 16 + (l & 15)) * 16));
#pragma unroll
    for (int r = 0; r < 4; r++)
#pragma unroll
      for (int c = 0; c < 4; c++) acc[r][c] = mfma_i8(af[r], bf[c], acc[r][c]);
  }

  // C/D layout: col = lane&15, row = (lane>>4)*4 + reg   [m89-verified]
  if (EPI == 0) {
    const float sx = scales[0];
#pragma unroll
    for (int c = 0; c < 4; c++) {
      int n = n0 + wn * 64 + c * 16 + (l & 15);
      int sec = n >> 10, o = n & 1023;
      float sy = sx * scales[1 + sec];
      const float* bias = (sec == 0) ? b0 : ((sec == 1) ? b1 : b2);
      float bb = bias[o];
      int h = o >> 6, hd = o & 63;
#pragma unroll
      for (int r = 0; r < 4; r++) {
        int mrow = m0 + wm * 64 + r * 16 + (l >> 4) * 4;
        int b = mrow >> 10, s = mrow & 1023;
        int bh = b * 16 + h;
        float y0 = (float)acc[r][c][0] * sy + bb;
        float y1 = (float)acc[r][c][1] * sy + bb;
        float y2 = (float)acc[r][c][2] * sy + bb;
        float y3 = (float)acc[r][c][3] * sy + bb;
        if (sec == 2) {  // V -> transposed [B,H,HD,S], 4 consecutive s: 8B st
          size_t base = ((size_t)(bh * 64 + hd)) * 1024 + s;
          ushort4 ph, pl;
          ph.x = f2bf(y0); pl.x = f2bf(y0 - bf2f(ph.x));
          ph.y = f2bf(y1); pl.y = f2bf(y1 - bf2f(ph.y));
          ph.z = f2bf(y2); pl.z = f2bf(y2 - bf2f(ph.z));
          ph.w = f2bf(y3); pl.w = f2bf(y3 - bf2f(ph.w));
          *(ushort4*)(vt_hi + base) = ph;
          *(ushort4*)(vt_lo + base) = pl;
        } else {        // Q/K -> [B,H,S,HD] hi/lo
          unsigned short* hb = (sec == 0) ? q_hi : k_hi;
          unsigned short* lb = (sec == 0) ? q_lo : k_lo;
          size_t base = ((size_t)bh * 1024 + s) * 64 + hd;
          unsigned short t;
          t = f2bf(y0); hb[base]       = t; lb[base]       = f2bf(y0 - bf2f(t));
          t = f2bf(y1); hb[base + 64]  = t; lb[base + 64]  = f2bf(y1 - bf2f(t));
          t = f2bf(y2); hb[base + 128] = t; lb[base + 128] = f2bf(y2 - bf2f(t));
          t = f2bf(y3); hb[base + 192] = t; lb[base + 192] = f2bf(y3 - bf2f(t));
        }
      }
    }
  } else {
    const float sy = scales[5] * scales[4];
#pragma unroll
    for (int c = 0; c < 4; c++) {
      int n = n0 + wn * 64 + c * 16 + (l & 15);
      float bb = b0[n];
#pragma unroll
      for (int r = 0; r < 4; r++) {
        int mrow = m0 + wm * 64 + r * 16 + (l >> 4) * 4;
        out[(size_t)(mrow)     * 1024 + n] = (float)acc[r][c][0] * sy + bb;
        out[(size_t)(mrow + 1) * 1024 + n] = (float)acc[r][c][1] * sy + bb;
        out[(size_t)(mrow + 2) * 1024 + n] = (float)acc[r][c][2] * sy + bb;
        out[(size_t)(mrow + 3) * 1024 + n] = (float)acc[r][c][3] * sy + bb;
      }
    }
  }
}

// --------------------------------------------------------------- attention
// block = (bh, 64-query tile), 4 waves x 16 q-rows. K/V tiles of 64 keys
// staged hi/lo via global_load_lds into fragment-major LDS. hi/lo-split
// bf16 MFMA (hh+hl+lh) for both QK^T and PV => ~2^-17 rel error.
__global__ __launch_bounds__(256) void attn_kernel(
    const unsigned short* __restrict__ Qh, const unsigned short* __restrict__ Ql,
    const unsigned short* __restrict__ Kh, const unsigned short* __restrict__ Kl,
    const unsigned short* __restrict__ Vh, const unsigned short* __restrict__ Vl,
    const float* __restrict__ amask, float* __restrict__ attn) {
  __shared__ __align__(16) unsigned short sKh[4096], sKl[4096];
  __shared__ __align__(16) unsigned short sVh[4096], sVl[4096];
  __shared__ __align__(16) float sP[64 * 68];  // pad-68: 2-way banks, 16B ok
  __shared__ float sMask[1024];
  const int tid = threadIdx.x, w = tid >> 6, l = tid & 63;
  const int qt = blockIdx.x, bh = blockIdx.y;
  const int b = bh >> 4, h = bh & 15;
  const int q0 = qt * 64;

  for (int j = tid; j < 1024; j += 256)
    sMask[j] = (1.0f - amask[b * 1024 + j]) * -10000.0f;

  // Stage Q tile through sK buffers, hoist A-fragments to registers.
#pragma unroll
  for (int i = 0; i < 2; i++) {
    int u = i * 4 + w;
    GLD16(Qh + (size_t)(bh * 1024 + q0 + l) * 64 + u * 8,
          (signed char*)sKh + u * 1024);
    GLD16(Ql + (size_t)(bh * 1024 + q0 + l) * 64 + u * 8,
          (signed char*)sKl + u * 1024);
  }
  __syncthreads();
  s16x8 aqh[2], aql[2];
#pragma unroll
  for (int c = 0; c < 2; c++) {
    int off = (c * 4 + (l >> 4)) * 1024 + (w * 16 + (l & 15)) * 16;
    aqh[c] = *(const s16x8*)((const signed char*)sKh + off);
    aql[c] = *(const s16x8*)((const signed char*)sKl + off);
  }

  const f32x4 zf = {0.f, 0.f, 0.f, 0.f};
  f32x4 o[4] = {zf, zf, zf, zf};
  float mrun[4] = {-INFINITY, -INFINITY, -INFINITY, -INFINITY};
  float lrun[4] = {0.f, 0.f, 0.f, 0.f};

  for (int kt = 0; kt < 16; kt++) {
    __syncthreads();  // prior reads done before restage
#pragma unroll
    for (int i = 0; i < 2; i++) {
      int u = i * 4 + w;
      size_t ke = (size_t)(bh * 1024 + kt * 64 + l) * 64 + u * 8;
      GLD16(Kh + ke, (signed char*)sKh + u * 1024);
      GLD16(Kl + ke, (signed char*)sKl + u * 1024);
      size_t ve = (size_t)(bh * 64 + l) * 1024 + kt * 64 + u * 8;
      GLD16(Vh + ve, (signed char*)sVh + u * 1024);
      GLD16(Vl + ve, (signed char*)sVl + u * 1024);
    }
    __syncthreads();

    // QK^T: scores[16q x 64k], 3-pass hi/lo
    f32x4 sc[4] = {zf, zf, zf, zf};
#pragma unroll
    for (int c = 0; c < 2; c++) {
#pragma unroll
      for (int ct = 0; ct < 4; ct++) {
        int boff = (c * 4 + (l >> 4)) * 1024 + (ct * 16 + (l & 15)) * 16;
        s16x8 kh = *(const s16x8*)((const signed char*)sKh + boff);
        s16x8 kl = *(const s16x8*)((const signed char*)sKl + boff);
        sc[ct] = mfma_bf16(aqh[c], kh, sc[ct]);
        sc[ct] = mfma_bf16(aqh[c], kl, sc[ct]);
        sc[ct] = mfma_bf16(aql[c], kh, sc[ct]);
      }
    }
    float msk[4];
#pragma unroll
    for (int ct = 0; ct < 4; ct++) msk[ct] = sMask[kt * 64 + ct * 16 + (l & 15)];
#pragma unroll
    for (int ct = 0; ct < 4; ct++) {
      sc[ct][0] = sc[ct][0] * 0.125f + msk[ct];
      sc[ct][1] = sc[ct][1] * 0.125f + msk[ct];
      sc[ct][2] = sc[ct][2] * 0.125f + msk[ct];
      sc[ct][3] = sc[ct][3] * 0.125f + msk[ct];
    }
    // online softmax; row r lives on the 16 lanes of this lane-group
    float p[4][4], fr[4];
#pragma unroll
    for (int r = 0; r < 4; r++) {
      float t = fmaxf(fmaxf(sc[0][r], sc[1][r]), fmaxf(sc[2][r], sc[3][r]));
#pragma unroll
      for (int s = 1; s < 16; s <<= 1) t = fmaxf(t, __shfl_xor(t, s, 64));
      float mn = fmaxf(mrun[r], t);
      fr[r] = expf(mrun[r] - mn);
      p[0][r] = expf(sc[0][r] - mn);
      p[1][r] = expf(sc[1][r] - mn);
      p[2][r] = expf(sc[2][r] - mn);
      p[3][r] = expf(sc[3][r] - mn);
      float ps = p[0][r] + p[1][r] + p[2][r] + p[3][r];
#pragma unroll
      for (int s = 1; s < 16; s <<= 1) ps += __shfl_xor(ps, s, 64);
      lrun[r] = lrun[r] * fr[r] + ps;
      mrun[r] = mn;
    }
#pragma unroll
    for (int t4 = 0; t4 < 4; t4++) {
      o[t4][0] *= fr[0]; o[t4][1] *= fr[1];
      o[t4][2] *= fr[2]; o[t4][3] *= fr[3];
    }
    // P through LDS (wave-private rows; same-wave ds order is safe)
#pragma unroll
    for (int ct = 0; ct < 4; ct++) {
      int prow = w * 16 + (l >> 4) * 4;
      int pcol = ct * 16 + (l & 15);
      sP[(prow)     * 68 + pcol] = p[ct][0];
      sP[(prow + 1) * 68 + pcol] = p[ct][1];
      sP[(prow + 2) * 68 + pcol] = p[ct][2];
      sP[(prow + 3) * 68 + pcol] = p[ct][3];
    }
    // PV: A = P (split hi/lo on the fly), B = V^T rows
#pragma unroll
    for (int c = 0; c < 2; c++) {
      const float* pr = sP + (w * 16 + (l & 15)) * 68 + c * 32 + (l >> 4) * 8;
      f32x4 x0 = *(const f32x4*)pr;
      f32x4 x1 = *(const f32x4*)(pr + 4);
      s16x8 pa_h, pa_l;
#pragma unroll
      for (int j = 0; j < 4; j++) {
        unsigned short hh = f2bf(x0[j]);
        pa_h[j] = (short)hh;
        pa_l[j] = (short)f2bf(x0[j] - bf2f(hh));
      }
#pragma unroll
      for (int j = 0; j < 4; j++) {
        unsigned short hh = f2bf(x1[j]);
        pa_h[4 + j] = (short)hh;
        pa_l[4 + j] = (short)f2bf(x1[j] - bf2f(hh));
      }
#pragma unroll
      for (int t4 = 0; t4 < 4; t4++) {
        int voff = (c * 4 + (l >> 4)) * 1024 + (t4 * 16 + (l & 15)) * 16;
        s16x8 vh = *(const s16x8*)((const signed char*)sVh + voff);
        s16x8 vl = *(const s16x8*)((const signed char*)sVl + voff);
        o[t4] = mfma_bf16(pa_h, vh, o[t4]);
        o[t4] = mfma_bf16(pa_h, vl, o[t4]);
        o[t4] = mfma_bf16(pa_l, vh, o[t4]);
      }
    }
  }

  float invl[4];
#pragma unroll
  for (int r = 0; r < 4; r++) invl[r] = 1.0f / lrun[r];
#pragma unroll
  for (int t4 = 0; t4 < 4; t4++) {
    int q = q0 + w * 16 + (l >> 4) * 4;
    size_t colb = (size_t)h * 64 + t4 * 16 + (l & 15);
    attn[((size_t)(b * 1024 + q))     * 1024 + colb] = o[t4][0] * invl[0];
    attn[((size_t)(b * 1024 + q + 1)) * 1024 + colb] = o[t4][1] * invl[1];
    attn[((size_t)(b * 1024 + q + 2)) * 1024 + colb] = o[t4][2] * invl[2];
    attn[((size_t)(b * 1024 + q + 3)) * 1024 + colb] = o[t4][3] * invl[3];
  }
}

// ------------------------------------------------------------------- launch
extern "C" void kernel_launch(void* const* d_in, const int* in_sizes, int n_in,
                              void* d_out, int out_size, void* d_ws,
                              size_t ws_size, hipStream_t stream) {
  const float* hs = (const float*)d_in[0];
  const float* am = (const float*)d_in[1];
  const float* Wq = (const float*)d_in[2];
  const float* bq = (const float*)d_in[3];
  const float* Wk = (const float*)d_in[4];
  const float* bk = (const float*)d_in[5];
  const float* Wv = (const float*)d_in[6];
  const float* bv = (const float*)d_in[7];
  const float* Wo = (const float*)d_in[8];
  const float* bo = (const float*)d_in[9];
  float* out = (float*)d_out;

  char* ws = (char*)d_ws;
  signed char* xi   = (signed char*)(ws);                 // 4 MiB (reused: ai)
  signed char* wqkv = (signed char*)(ws + (4u << 20));    // 3 MiB
  signed char* woq  = (signed char*)(ws + (7u << 20));    // 1 MiB
  unsigned short* qhi  = (unsigned short*)(ws + (8u << 20));
  unsigned short* qlo  = (unsigned short*)(ws + (16u << 20));
  unsigned short* khi  = (unsigned short*)(ws + (24u << 20));
  unsigned short* klo  = (unsigned short*)(ws + (32u << 20));
  unsigned short* vthi = (unsigned short*)(ws + (40u << 20));
  unsigned short* vtlo = (unsigned short*)(ws + (48u << 20));
  float* attn = (float*)(ws + (56u << 20));               // 16 MiB
  signed char* ai = xi;                                   // reuse region
  float* partials = (float*)(ws + (72u << 20));           // 6*64 floats
  float* scales = partials + 6 * 64;                      // 6 floats

  absmax_partial<<<64, 256, 0, stream>>>(hs, 1 << 20, partials + 0);
  absmax_partial<<<64, 256, 0, stream>>>(Wq, 1 << 18, partials + 64);
  absmax_partial<<<64, 256, 0, stream>>>(Wk, 1 << 18, partials + 128);
  absmax_partial<<<64, 256, 0, stream>>>(Wv, 1 << 18, partials + 192);
  absmax_partial<<<64, 256, 0, stream>>>(Wo, 1 << 18, partials + 256);
  finalize_scales<<<1, 320, 0, stream>>>(partials, scales, 5);
  quantize_kernel<<<512, 256, 0, stream>>>(hs, xi, scales + 0, 1 << 20);
  quantize_kernel<<<256, 256, 0, stream>>>(Wq, wqkv, scales + 1, 1 << 18);
  quantize_kernel<<<256, 256, 0, stream>>>(Wk, wqkv + (1 << 20), scales + 2, 1 << 18);
  quantize_kernel<<<256, 256, 0, stream>>>(Wv, wqkv + (2 << 20), scales + 3, 1 << 18);
  quantize_kernel<<<256, 256, 0, stream>>>(Wo, woq, scales + 4, 1 << 18);
  gemm_i8_kernel<0><<<dim3(24, 32), 256, 0, stream>>>(
      xi, wqkv, scales, bq, bk, bv, qhi, qlo, khi, klo, vthi, vtlo, nullptr);
  attn_kernel<<<dim3(16, 64), 256, 0, stream>>>(qhi, qlo, khi, klo, vthi, vtlo,
                                                am, attn);
  absmax_partial<<<64, 256, 0, stream>>>(attn, 1 << 20, partials + 320);
  finalize_scales<<<1, 64, 0, stream>>>(partials + 320, scales + 5, 1);
  quantize_kernel<<<512, 256, 0, stream>>>(attn, ai, scales + 5, 1 << 20);
  gemm_i8_kernel<1><<<dim3(8, 32), 256, 0, stream>>>(
      ai, woq, scales, bo, nullptr, nullptr, nullptr, nullptr, nullptr,
      nullptr, nullptr, nullptr, out);
}

// Round 2
// 281.869 us; speedup vs baseline: 1.3130x; 1.3130x over previous
//
#include <hip/hip_runtime.h>
#include <cmath>

// GPT2QuantAttention on MI355X (gfx950).
// B=4 S=1024 D=1024 H=16 HD=64, 8-bit per-tensor symmetric fake-quant.
//
// R2 changes vs R1 (attn was 159us @ 21% occupancy, MfmaUtil 13.6%):
//   - attn: sMask removed from LDS (global per-tile mask loads) -> 49KB LDS
//     -> 3 blocks/CU; __expf softmax; truncation-based P hi/lo split (4 ops);
//     XCD-aware block swizzle (8 bh per XCD = 4MB K/V = exactly one L2).
//   - gemms: 2-phase double-buffered pipeline (stage next tile before
//     ds_read+MFMA, single __syncthreads per K-step) + XCD swizzle.
//   - absmax/quantize fused: 16 launches -> 9, grids 64 -> 256+.
//
// ws map (bytes):
//   [0,4M)    xi int8 (also reused as ai int8 for the output GEMM)
//   [4M,7M)   wqkv int8 (Wq|Wk|Wv stacked rows)
//   [7M,8M)   wo int8
//   [8M..56M) Qhi Qlo Khi Klo VThi VTlo (8M each, bf16)
//   [56M,72M) attn fp32 [4096,1024]
//   [72M+..)  partials[6][256], scales[6]

using f32x4 = __attribute__((ext_vector_type(4))) float;
using i32x4 = __attribute__((ext_vector_type(4))) int;
using s16x8 = __attribute__((ext_vector_type(8))) short;

#define DI __device__ __forceinline__

DI unsigned short f2bf(float x) {  // fp32 -> bf16, round-to-nearest-even
  unsigned u = __float_as_uint(x);
  return (unsigned short)((u + 0x7FFFu + ((u >> 16) & 1u)) >> 16);
}
DI float bf2f(unsigned short h) { return __uint_as_float(((unsigned)h) << 16); }

DI f32x4 mfma_bf16(s16x8 a, s16x8 b, f32x4 c) {
  return __builtin_amdgcn_mfma_f32_16x16x32_bf16(a, b, c, 0, 0, 0);
}
DI i32x4 mfma_i8(i32x4 a, i32x4 b, i32x4 c) {
  return __builtin_amdgcn_mfma_i32_16x16x64_i8(a, b, c, 0, 0, 0);
}

// global->LDS direct copy, 16B per lane. LDS dst = wave-uniform base + lane*16.
#define GLD16(gp, sp)                                                        \
  __builtin_amdgcn_global_load_lds(                                          \
      (__attribute__((address_space(1))) void*)(unsigned long long)(gp),     \
      (__attribute__((address_space(3))) void*)(unsigned long long)(sp),     \
      16, 0, 0)

// ---------------------------------------------------------------- reductions
DI float wave_block_max(float m, int tid) {  // 256-thread block max
#pragma unroll
  for (int s = 1; s < 64; s <<= 1) m = fmaxf(m, __shfl_xor(m, s, 64));
  __shared__ float sm[4];
  if ((tid & 63) == 0) sm[tid >> 6] = m;
  __syncthreads();
  return fmaxf(fmaxf(sm[0], sm[1]), fmaxf(sm[2], sm[3]));
}

__global__ __launch_bounds__(256) void absmax_partial(
    const float* __restrict__ x, int n4, float* __restrict__ out) {
  float m = 0.f;
  const int stride = gridDim.x * blockDim.x;
  for (int i = blockIdx.x * blockDim.x + threadIdx.x; i < n4; i += stride) {
    f32x4 v = ((const f32x4*)x)[i];
    m = fmaxf(m, fmaxf(fmaxf(fabsf(v[0]), fabsf(v[1])),
                       fmaxf(fabsf(v[2]), fabsf(v[3]))));
  }
  m = wave_block_max(m, threadIdx.x);
  if (threadIdx.x == 0) out[blockIdx.x] = m;
}

// 5 tensors in one launch: y=0 -> hs (1M f32x4), y=1..4 -> weights (256K).
__global__ __launch_bounds__(256) void absmax5_kernel(
    const float* __restrict__ t0, const float* __restrict__ t1,
    const float* __restrict__ t2, const float* __restrict__ t3,
    const float* __restrict__ t4, float* __restrict__ partials) {
  const int y = blockIdx.y;
  const float* x = (y == 0) ? t0 : (y == 1) ? t1 : (y == 2) ? t2
                                             : (y == 3) ? t3 : t4;
  const int n4 = (y == 0) ? (1 << 20) : (1 << 18);
  float m = 0.f;
  const int stride = gridDim.x * 256;
  for (int i = blockIdx.x * 256 + threadIdx.x; i < n4; i += stride) {
    f32x4 v = ((const f32x4*)x)[i];
    m = fmaxf(m, fmaxf(fmaxf(fabsf(v[0]), fabsf(v[1])),
                       fmaxf(fabsf(v[2]), fabsf(v[3]))));
  }
  m = wave_block_max(m, threadIdx.x);
  if (threadIdx.x == 0) partials[y * 256 + blockIdx.x] = m;
}

// One block per tensor: reduce 256 partials -> scale.
__global__ __launch_bounds__(256) void finalize_kernel(
    const float* __restrict__ partials, float* __restrict__ scales) {
  const int t = blockIdx.x;
  float m = partials[t * 256 + threadIdx.x];
  m = wave_block_max(m, threadIdx.x);
  if (threadIdx.x == 0) scales[t] = fmaxf(m / 127.0f, 1e-8f);
}

DI int quant1(float v, float s) {
  float r = rintf(v / s);  // IEEE div + RNE: matches jnp round-half-even
  r = fminf(fmaxf(r, -127.f), 127.f);
  return ((int)r) & 0xFF;
}

__global__ __launch_bounds__(256) void quantize_kernel(
    const float* __restrict__ x, signed char* __restrict__ q,
    const float* __restrict__ scale_p, int n4) {
  const float s = scale_p[0];
  const int stride = gridDim.x * blockDim.x;
  for (int i = blockIdx.x * blockDim.x + threadIdx.x; i < n4; i += stride) {
    f32x4 v = ((const f32x4*)x)[i];
    int packed = quant1(v[0], s) | (quant1(v[1], s) << 8) |
                 (quant1(v[2], s) << 16) | (quant1(v[3], s) << 24);
    ((int*)q)[i] = packed;
  }
}

__global__ __launch_bounds__(256) void quant5_kernel(
    const float* __restrict__ t0, const float* __restrict__ t1,
    const float* __restrict__ t2, const float* __restrict__ t3,
    const float* __restrict__ t4, signed char* __restrict__ xi,
    signed char* __restrict__ wqkv, signed char* __restrict__ woq,
    const float* __restrict__ scales) {
  const int y = blockIdx.y;
  const float* x = (y == 0) ? t0 : (y == 1) ? t1 : (y == 2) ? t2
                                             : (y == 3) ? t3 : t4;
  const int n4 = (y == 0) ? (1 << 20) : (1 << 18);
  signed char* q = (y == 0) ? xi
                 : (y == 4) ? woq
                            : wqkv + ((size_t)(y - 1) << 20);
  const float s = scales[y];
  const int stride = gridDim.x * 256;
  for (int i = blockIdx.x * 256 + threadIdx.x; i < n4; i += stride) {
    f32x4 v = ((const f32x4*)x)[i];
    int packed = quant1(v[0], s) | (quant1(v[1], s) << 8) |
                 (quant1(v[2], s) << 16) | (quant1(v[3], s) << 24);
    ((int*)q)[i] = packed;
  }
}

// ------------------------------------------------------------------ i8 GEMM
// C[m,n] = sum_k A[m,k]*Bw[n,k], 128x128 tile, 4 waves (2x2), K-step 64B.
// 2-phase pipeline: stage(next) issued before ds_read+MFMA(cur); single
// __syncthreads (implicit vmcnt(0) drain) per K-step. LDS fragment-major.
template <int EPI>
__global__ __launch_bounds__(256) void gemm_i8_kernel(
    const signed char* __restrict__ A, const signed char* __restrict__ Bw,
    const float* __restrict__ scales, const float* __restrict__ b0,
    const float* __restrict__ b1, const float* __restrict__ b2,
    unsigned short* __restrict__ q_hi, unsigned short* __restrict__ q_lo,
    unsigned short* __restrict__ k_hi, unsigned short* __restrict__ k_lo,
    unsigned short* __restrict__ vt_hi, unsigned short* __restrict__ vt_lo,
    float* __restrict__ out) {
  __shared__ __align__(16) signed char sA[2][8192];
  __shared__ __align__(16) signed char sB[2][8192];
  const int tid = threadIdx.x, w = tid >> 6, l = tid & 63;
  // XCD-aware bijective swizzle (grid % 8 == 0 in both instantiations)
  const int NX = EPI ? 8 : 24;
  const int NB = EPI ? 256 : 768;
  const int id = blockIdx.x;
  const int vb = (id & 7) * (NB >> 3) + (id >> 3);
  const int m0 = (vb / NX) * 128, n0 = (vb % NX) * 128;
  const int wm = w >> 1, wn = w & 1;
  const i32x4 zi = {0, 0, 0, 0};
  i32x4 acc[4][4];
#pragma unroll
  for (int r = 0; r < 4; r++)
#pragma unroll
    for (int c = 0; c < 4; c++) acc[r][c] = zi;

#define GSTAGE(bi, kb)                                                       \
  {                                                                          \
    _Pragma("unroll") for (int i = 0; i < 2; i++) {                          \
      int u = i * 4 + w; /* wave-uniform */                                  \
      int slot = u >> 1, row = (u & 1) * 64 + l;                             \
      GLD16(A + (size_t)(m0 + row) * 1024 + (kb) + slot * 16,                \
            sA[bi] + u * 1024);                                              \
      GLD16(Bw + (size_t)(n0 + row) * 1024 + (kb) + slot * 16,               \
            sB[bi] + u * 1024);                                              \
    }                                                                        \
  }

  GSTAGE(0, 0);
  for (int kt = 0; kt < 16; kt++) {
    __syncthreads();  // drains stage(kt) + guarantees buf(kt&1^1) reads done
    if (kt < 15) GSTAGE((kt & 1) ^ 1, (kt + 1) * 64);
    const signed char* pA = sA[kt & 1];
    const signed char* pB = sB[kt & 1];
    i32x4 af[4], bf[4];
#pragma unroll
    for (int r = 0; r < 4; r++)
      af[r] = *(const i32x4*)(pA + ((l >> 4) * 2048 +
                                    (wm * 64 + r * 16 + (l & 15)) * 16));
#pragma unroll
    for (int c = 0; c < 4; c++)
      bf[c] = *(const i32x4*)(pB + ((l >> 4) * 2048 +
                                    (wn * 64 + c * 16 + (l & 15)) * 16));
#pragma unroll
    for (int r = 0; r < 4; r++)
#pragma unroll
      for (int c = 0; c < 4; c++) acc[r][c] = mfma_i8(af[r], bf[c], acc[r][c]);
  }
#undef GSTAGE

  // C/D layout: col = lane&15, row = (lane>>4)*4 + reg   [m89-verified]
  if (EPI == 0) {
    const float sx = scales[0];
#pragma unroll
    for (int c = 0; c < 4; c++) {
      int n = n0 + wn * 64 + c * 16 + (l & 15);
      int sec = n >> 10, o = n & 1023;
      float sy = sx * scales[1 + sec];
      const float* bias = (sec == 0) ? b0 : ((sec == 1) ? b1 : b2);
      float bb = bias[o];
      int h = o >> 6, hd = o & 63;
#pragma unroll
      for (int r = 0; r < 4; r++) {
        int mrow = m0 + wm * 64 + r * 16 + (l >> 4) * 4;
        int b = mrow >> 10, s = mrow & 1023;
        int bh = b * 16 + h;
        float y0 = (float)acc[r][c][0] * sy + bb;
        float y1 = (float)acc[r][c][1] * sy + bb;
        float y2 = (float)acc[r][c][2] * sy + bb;
        float y3 = (float)acc[r][c][3] * sy + bb;
        if (sec == 2) {  // V -> transposed [B,H,HD,S], 4 consecutive s
          size_t base = ((size_t)(bh * 64 + hd)) * 1024 + s;
          ushort4 ph, pl;
          ph.x = f2bf(y0); pl.x = f2bf(y0 - bf2f(ph.x));
          ph.y = f2bf(y1); pl.y = f2bf(y1 - bf2f(ph.y));
          ph.z = f2bf(y2); pl.z = f2bf(y2 - bf2f(ph.z));
          ph.w = f2bf(y3); pl.w = f2bf(y3 - bf2f(ph.w));
          *(ushort4*)(vt_hi + base) = ph;
          *(ushort4*)(vt_lo + base) = pl;
        } else {        // Q/K -> [B,H,S,HD] hi/lo
          unsigned short* hb = (sec == 0) ? q_hi : k_hi;
          unsigned short* lb = (sec == 0) ? q_lo : k_lo;
          size_t base = ((size_t)bh * 1024 + s) * 64 + hd;
          unsigned short t;
          t = f2bf(y0); hb[base]       = t; lb[base]       = f2bf(y0 - bf2f(t));
          t = f2bf(y1); hb[base + 64]  = t; lb[base + 64]  = f2bf(y1 - bf2f(t));
          t = f2bf(y2); hb[base + 128] = t; lb[base + 128] = f2bf(y2 - bf2f(t));
          t = f2bf(y3); hb[base + 192] = t; lb[base + 192] = f2bf(y3 - bf2f(t));
        }
      }
    }
  } else {
    const float sy = scales[5] * scales[4];
#pragma unroll
    for (int c = 0; c < 4; c++) {
      int n = n0 + wn * 64 + c * 16 + (l & 15);
      float bb = b0[n];
#pragma unroll
      for (int r = 0; r < 4; r++) {
        int mrow = m0 + wm * 64 + r * 16 + (l >> 4) * 4;
        out[(size_t)(mrow)     * 1024 + n] = (float)acc[r][c][0] * sy + bb;
        out[(size_t)(mrow + 1) * 1024 + n] = (float)acc[r][c][1] * sy + bb;
        out[(size_t)(mrow + 2) * 1024 + n] = (float)acc[r][c][2] * sy + bb;
        out[(size_t)(mrow + 3) * 1024 + n] = (float)acc[r][c][3] * sy + bb;
      }
    }
  }
}

// --------------------------------------------------------------- attention
// block = (bh, 64-query tile), 4 waves x 16 q-rows. LDS 49KB -> 3 blocks/CU.
// hi/lo-split bf16 MFMA (hh+hl+lh) for QK^T and PV => ~2^-16 rel error.
__global__ __launch_bounds__(256) void attn_kernel(
    const unsigned short* __restrict__ Qh, const unsigned short* __restrict__ Ql,
    const unsigned short* __restrict__ Kh, const unsigned short* __restrict__ Kl,
    const unsigned short* __restrict__ Vh, const unsigned short* __restrict__ Vl,
    const float* __restrict__ amask, float* __restrict__ attn) {
  __shared__ __align__(16) unsigned short sKh[4096], sKl[4096];
  __shared__ __align__(16) unsigned short sVh[4096], sVl[4096];
  __shared__ __align__(16) float sP[64 * 68];
  const int tid = threadIdx.x, w = tid >> 6, l = tid & 63;
  // XCD swizzle: 8 consecutive bh per XCD -> K/V working set = 4MB = one L2.
  const int id = blockIdx.x;              // 0..1023
  const int v = (id & 7) * 128 + (id >> 3);
  const int qt = v & 15, bh = v >> 4;
  const int b = bh >> 4, h = bh & 15;
  const int q0 = qt * 64;

  // Stage Q tile through sK buffers, hoist A-fragments to registers.
#pragma unroll
  for (int i = 0; i < 2; i++) {
    int u = i * 4 + w;
    GLD16(Qh + (size_t)(bh * 1024 + q0 + l) * 64 + u * 8,
          (signed char*)sKh + u * 1024);
    GLD16(Ql + (size_t)(bh * 1024 + q0 + l) * 64 + u * 8,
          (signed char*)sKl + u * 1024);
  }
  __syncthreads();
  s16x8 aqh[2], aql[2];
#pragma unroll
  for (int c = 0; c < 2; c++) {
    int off = (c * 4 + (l >> 4)) * 1024 + (w * 16 + (l & 15)) * 16;
    aqh[c] = *(const s16x8*)((const signed char*)sKh + off);
    aql[c] = *(const s16x8*)((const signed char*)sKl + off);
  }

  const f32x4 zf = {0.f, 0.f, 0.f, 0.f};
  f32x4 o[4] = {zf, zf, zf, zf};
  float mrun[4] = {-INFINITY, -INFINITY, -INFINITY, -INFINITY};
  float lrun[4] = {0.f, 0.f, 0.f, 0.f};

  for (int kt = 0; kt < 16; kt++) {
    // mask values for this tile: global loads, hidden under staging drain
    float mk[4];
#pragma unroll
    for (int ct = 0; ct < 4; ct++)
      mk[ct] = amask[b * 1024 + kt * 64 + ct * 16 + (l & 15)];
    __syncthreads();  // prior reads done before restage
#pragma unroll
    for (int i = 0; i < 2; i++) {
      int u = i * 4 + w;
      size_t ke = (size_t)(bh * 1024 + kt * 64 + l) * 64 + u * 8;
      GLD16(Kh + ke, (signed char*)sKh + u * 1024);
      GLD16(Kl + ke, (signed char*)sKl + u * 1024);
      size_t ve = (size_t)(bh * 64 + l) * 1024 + kt * 64 + u * 8;
      GLD16(Vh + ve, (signed char*)sVh + u * 1024);
      GLD16(Vl + ve, (signed char*)sVl + u * 1024);
    }
    __syncthreads();

    // QK^T: scores[16q x 64k], 3-pass hi/lo
    f32x4 sc[4] = {zf, zf, zf, zf};
#pragma unroll
    for (int c = 0; c < 2; c++) {
#pragma unroll
      for (int ct = 0; ct < 4; ct++) {
        int boff = (c * 4 + (l >> 4)) * 1024 + (ct * 16 + (l & 15)) * 16;
        s16x8 kh = *(const s16x8*)((const signed char*)sKh + boff);
        s16x8 kl = *(const s16x8*)((const signed char*)sKl + boff);
        sc[ct] = mfma_bf16(aqh[c], kh, sc[ct]);
        sc[ct] = mfma_bf16(aqh[c], kl, sc[ct]);
        sc[ct] = mfma_bf16(aql[c], kh, sc[ct]);
      }
    }
#pragma unroll
    for (int ct = 0; ct < 4; ct++) {
      float msk = (1.0f - mk[ct]) * -10000.0f;
      sc[ct][0] = sc[ct][0] * 0.125f + msk;
      sc[ct][1] = sc[ct][1] * 0.125f + msk;
      sc[ct][2] = sc[ct][2] * 0.125f + msk;
      sc[ct][3] = sc[ct][3] * 0.125f + msk;
    }
    // online softmax; row r lives on the 16 lanes of this lane-group
    float p[4][4], fr[4];
#pragma unroll
    for (int r = 0; r < 4; r++) {
      float t = fmaxf(fmaxf(sc[0][r], sc[1][r]), fmaxf(sc[2][r], sc[3][r]));
#pragma unroll
      for (int s = 1; s < 16; s <<= 1) t = fmaxf(t, __shfl_xor(t, s, 64));
      float mn = fmaxf(mrun[r], t);
      fr[r] = __expf(mrun[r] - mn);
      p[0][r] = __expf(sc[0][r] - mn);
      p[1][r] = __expf(sc[1][r] - mn);
      p[2][r] = __expf(sc[2][r] - mn);
      p[3][r] = __expf(sc[3][r] - mn);
      float ps = p[0][r] + p[1][r] + p[2][r] + p[3][r];
#pragma unroll
      for (int s = 1; s < 16; s <<= 1) ps += __shfl_xor(ps, s, 64);
      lrun[r] = lrun[r] * fr[r] + ps;
      mrun[r] = mn;
    }
#pragma unroll
    for (int t4 = 0; t4 < 4; t4++) {
      o[t4][0] *= fr[0]; o[t4][1] *= fr[1];
      o[t4][2] *= fr[2]; o[t4][3] *= fr[3];
    }
    // P through LDS (wave-private rows; same-wave ds order is safe)
#pragma unroll
    for (int ct = 0; ct < 4; ct++) {
      int prow = w * 16 + (l >> 4) * 4;
      int pcol = ct * 16 + (l & 15);
      sP[(prow)     * 68 + pcol] = p[ct][0];
      sP[(prow + 1) * 68 + pcol] = p[ct][1];
      sP[(prow + 2) * 68 + pcol] = p[ct][2];
      sP[(prow + 3) * 68 + pcol] = p[ct][3];
    }
    // PV: A = P (truncation hi/lo split: 4 ops, pair err ~2^-16), B = V^T
#pragma unroll
    for (int c = 0; c < 2; c++) {
      const float* pr = sP + (w * 16 + (l & 15)) * 68 + c * 32 + (l >> 4) * 8;
      f32x4 x0 = *(const f32x4*)pr;
      f32x4 x1 = *(const f32x4*)(pr + 4);
      s16x8 pa_h, pa_l;
#pragma unroll
      for (int j = 0; j < 4; j++) {
        unsigned u = __float_as_uint(x0[j]);
        pa_h[j] = (short)(u >> 16);
        float rr = x0[j] - __uint_as_float(u & 0xFFFF0000u);
        pa_l[j] = (short)(__float_as_uint(rr) >> 16);
      }
#pragma unroll
      for (int j = 0; j < 4; j++) {
        unsigned u = __float_as_uint(x1[j]);
        pa_h[4 + j] = (short)(u >> 16);
        float rr = x1[j] - __uint_as_float(u & 0xFFFF0000u);
        pa_l[4 + j] = (short)(__float_as_uint(rr) >> 16);
      }
#pragma unroll
      for (int t4 = 0; t4 < 4; t4++) {
        int voff = (c * 4 + (l >> 4)) * 1024 + (t4 * 16 + (l & 15)) * 16;
        s16x8 vh = *(const s16x8*)((const signed char*)sVh + voff);
        s16x8 vl = *(const s16x8*)((const signed char*)sVl + voff);
        o[t4] = mfma_bf16(pa_h, vh, o[t4]);
        o[t4] = mfma_bf16(pa_h, vl, o[t4]);
        o[t4] = mfma_bf16(pa_l, vh, o[t4]);
      }
    }
  }

  float invl[4];
#pragma unroll
  for (int r = 0; r < 4; r++) invl[r] = 1.0f / lrun[r];
#pragma unroll
  for (int t4 = 0; t4 < 4; t4++) {
    int q = q0 + w * 16 + (l >> 4) * 4;
    size_t colb = (size_t)h * 64 + t4 * 16 + (l & 15);
    attn[((size_t)(b * 1024 + q))     * 1024 + colb] = o[t4][0] * invl[0];
    attn[((size_t)(b * 1024 + q + 1)) * 1024 + colb] = o[t4][1] * invl[1];
    attn[((size_t)(b * 1024 + q + 2)) * 1024 + colb] = o[t4][2] * invl[2];
    attn[((size_t)(b * 1024 + q + 3)) * 1024 + colb] = o[t4][3] * invl[3];
  }
}

// ------------------------------------------------------------------- launch
extern "C" void kernel_launch(void* const* d_in, const int* in_sizes, int n_in,
                              void* d_out, int out_size, void* d_ws,
                              size_t ws_size, hipStream_t stream) {
  const float* hs = (const float*)d_in[0];
  const float* am = (const float*)d_in[1];
  const float* Wq = (const float*)d_in[2];
  const float* bq = (const float*)d_in[3];
  const float* Wk = (const float*)d_in[4];
  const float* bk = (const float*)d_in[5];
  const float* Wv = (const float*)d_in[6];
  const float* bv = (const float*)d_in[7];
  const float* Wo = (const float*)d_in[8];
  const float* bo = (const float*)d_in[9];
  float* out = (float*)d_out;

  char* ws = (char*)d_ws;
  signed char* xi   = (signed char*)(ws);                 // 4 MiB (reused: ai)
  signed char* wqkv = (signed char*)(ws + (4u << 20));    // 3 MiB
  signed char* woq  = (signed char*)(ws + (7u << 20));    // 1 MiB
  unsigned short* qhi  = (unsigned short*)(ws + (8u << 20));
  unsigned short* qlo  = (unsigned short*)(ws + (16u << 20));
  unsigned short* khi  = (unsigned short*)(ws + (24u << 20));
  unsigned short* klo  = (unsigned short*)(ws + (32u << 20));
  unsigned short* vthi = (unsigned short*)(ws + (40u << 20));
  unsigned short* vtlo = (unsigned short*)(ws + (48u << 20));
  float* attn = (float*)(ws + (56u << 20));               // 16 MiB
  signed char* ai = xi;                                   // reuse region
  float* partials = (float*)(ws + (72u << 20));           // 6*256 floats
  float* scales = partials + 6 * 256;                     // 6 floats

  absmax5_kernel<<<dim3(256, 5), 256, 0, stream>>>(hs, Wq, Wk, Wv, Wo,
                                                   partials);
  finalize_kernel<<<5, 256, 0, stream>>>(partials, scales);
  quant5_kernel<<<dim3(256, 5), 256, 0, stream>>>(hs, Wq, Wk, Wv, Wo, xi,
                                                  wqkv, woq, scales);
  gemm_i8_kernel<0><<<768, 256, 0, stream>>>(
      xi, wqkv, scales, bq, bk, bv, qhi, qlo, khi, klo, vthi, vtlo, nullptr);
  attn_kernel<<<1024, 256, 0, stream>>>(qhi, qlo, khi, klo, vthi, vtlo, am,
                                        attn);
  absmax_partial<<<256, 256, 0, stream>>>(attn, 1 << 20, partials + 5 * 256);
  finalize_kernel<<<1, 256, 0, stream>>>(partials + 5 * 256, scales + 5);
  quantize_kernel<<<512, 256, 0, stream>>>(attn, ai, scales + 5, 1 << 20);
  gemm_i8_kernel<1><<<256, 256, 0, stream>>>(
      ai, woq, scales, bo, nullptr, nullptr, nullptr, nullptr, nullptr,
      nullptr, nullptr, nullptr, out);
}

// Round 3
// 236.632 us; speedup vs baseline: 1.5640x; 1.1912x over previous
//
#include <hip/hip_runtime.h>
#include <cmath>

// GPT2QuantAttention on MI355X (gfx950).
// B=4 S=1024 D=1024 H=16 HD=64, 8-bit per-tensor symmetric fake-quant.
//
// R3 changes vs R2 (attn was 127us @ MfmaUtil 16.5%, VALU 30%, Occ 22%):
//   attn rewritten:
//   - swapped QK^T: mfma(A=K, B=Q) -> P is lane-local per q-column; softmax
//     reduce = 15 fmax + 2 shfl_xor (was 32 shfls); sP LDS buffer DELETED
//     (P feeds PV A-operand directly in registers: pack kb-pairs so one
//     16x16x32 mfma covers 32 keys; A/B k-slot maps match exactly).
//   - QBLK=128 (each of 4 waves owns 32 q): K/V fragments read once per wave
//     serve 2 q-sub-blocks -> LDS read amplification halved.
//   - K/V double-buffered in LDS, staged with global_load_lds + counted
//     s_waitcnt vmcnt(8) across raw s_barriers (loads in flight over the
//     barrier; no vmcnt(0) drain in the main loop).
//   - LDS 64KB, 2 blocks/CU, grid 512 fully resident, launch_bounds(256,2).
//
// ws map (bytes):
//   [0,4M)    xi int8 (also reused as ai int8 for the output GEMM)
//   [4M,7M)   wqkv int8 (Wq|Wk|Wv stacked rows)
//   [7M,8M)   wo int8
//   [8M..56M) Qhi Qlo Khi Klo VThi VTlo (8M each, bf16)
//   [56M,72M) attn fp32 [4096,1024]
//   [72M+..)  partials[6][256], scales[6]

using f32x4 = __attribute__((ext_vector_type(4))) float;
using i32x4 = __attribute__((ext_vector_type(4))) int;
using s16x4 = __attribute__((ext_vector_type(4))) short;
using s16x8 = __attribute__((ext_vector_type(8))) short;

#define DI __device__ __forceinline__

DI unsigned short f2bf(float x) {  // fp32 -> bf16, round-to-nearest-even
  unsigned u = __float_as_uint(x);
  return (unsigned short)((u + 0x7FFFu + ((u >> 16) & 1u)) >> 16);
}
DI float bf2f(unsigned short h) { return __uint_as_float(((unsigned)h) << 16); }

DI f32x4 mfma_bf16(s16x8 a, s16x8 b, f32x4 c) {
  return __builtin_amdgcn_mfma_f32_16x16x32_bf16(a, b, c, 0, 0, 0);
}
DI i32x4 mfma_i8(i32x4 a, i32x4 b, i32x4 c) {
  return __builtin_amdgcn_mfma_i32_16x16x64_i8(a, b, c, 0, 0, 0);
}

// truncation hi/lo bf16 split (4 ops; pair error ~2^-16 relative)
DI void bfsplit(float x, short& hi, short& lo) {
  unsigned u = __float_as_uint(x);
  hi = (short)(u >> 16);
  float r = x - __uint_as_float(u & 0xFFFF0000u);
  lo = (short)(__float_as_uint(r) >> 16);
}

// global->LDS direct copy, 16B per lane. LDS dst = wave-uniform base + lane*16.
#define GLD16(gp, sp)                                                        \
  __builtin_amdgcn_global_load_lds(                                          \
      (__attribute__((address_space(1))) void*)(unsigned long long)(gp),     \
      (__attribute__((address_space(3))) void*)(unsigned long long)(sp),     \
      16, 0, 0)

// ---------------------------------------------------------------- reductions
DI float wave_block_max(float m, int tid) {  // 256-thread block max
#pragma unroll
  for (int s = 1; s < 64; s <<= 1) m = fmaxf(m, __shfl_xor(m, s, 64));
  __shared__ float sm[4];
  if ((tid & 63) == 0) sm[tid >> 6] = m;
  __syncthreads();
  return fmaxf(fmaxf(sm[0], sm[1]), fmaxf(sm[2], sm[3]));
}

__global__ __launch_bounds__(256) void absmax_partial(
    const float* __restrict__ x, int n4, float* __restrict__ out) {
  float m = 0.f;
  const int stride = gridDim.x * blockDim.x;
  for (int i = blockIdx.x * blockDim.x + threadIdx.x; i < n4; i += stride) {
    f32x4 v = ((const f32x4*)x)[i];
    m = fmaxf(m, fmaxf(fmaxf(fabsf(v[0]), fabsf(v[1])),
                       fmaxf(fabsf(v[2]), fabsf(v[3]))));
  }
  m = wave_block_max(m, threadIdx.x);
  if (threadIdx.x == 0) out[blockIdx.x] = m;
}

// 5 tensors in one launch: y=0 -> hs (1M f32x4), y=1..4 -> weights (256K).
__global__ __launch_bounds__(256) void absmax5_kernel(
    const float* __restrict__ t0, const float* __restrict__ t1,
    const float* __restrict__ t2, const float* __restrict__ t3,
    const float* __restrict__ t4, float* __restrict__ partials) {
  const int y = blockIdx.y;
  const float* x = (y == 0) ? t0 : (y == 1) ? t1 : (y == 2) ? t2
                                             : (y == 3) ? t3 : t4;
  const int n4 = (y == 0) ? (1 << 20) : (1 << 18);
  float m = 0.f;
  const int stride = gridDim.x * 256;
  for (int i = blockIdx.x * 256 + threadIdx.x; i < n4; i += stride) {
    f32x4 v = ((const f32x4*)x)[i];
    m = fmaxf(m, fmaxf(fmaxf(fabsf(v[0]), fabsf(v[1])),
                       fmaxf(fabsf(v[2]), fabsf(v[3]))));
  }
  m = wave_block_max(m, threadIdx.x);
  if (threadIdx.x == 0) partials[y * 256 + blockIdx.x] = m;
}

__global__ __launch_bounds__(256) void finalize_kernel(
    const float* __restrict__ partials, float* __restrict__ scales) {
  const int t = blockIdx.x;
  float m = partials[t * 256 + threadIdx.x];
  m = wave_block_max(m, threadIdx.x);
  if (threadIdx.x == 0) scales[t] = fmaxf(m / 127.0f, 1e-8f);
}

DI int quant1(float v, float s) {
  float r = rintf(v / s);  // IEEE div + RNE: matches jnp round-half-even
  r = fminf(fmaxf(r, -127.f), 127.f);
  return ((int)r) & 0xFF;
}

__global__ __launch_bounds__(256) void quantize_kernel(
    const float* __restrict__ x, signed char* __restrict__ q,
    const float* __restrict__ scale_p, int n4) {
  const float s = scale_p[0];
  const int stride = gridDim.x * blockDim.x;
  for (int i = blockIdx.x * blockDim.x + threadIdx.x; i < n4; i += stride) {
    f32x4 v = ((const f32x4*)x)[i];
    int packed = quant1(v[0], s) | (quant1(v[1], s) << 8) |
                 (quant1(v[2], s) << 16) | (quant1(v[3], s) << 24);
    ((int*)q)[i] = packed;
  }
}

__global__ __launch_bounds__(256) void quant5_kernel(
    const float* __restrict__ t0, const float* __restrict__ t1,
    const float* __restrict__ t2, const float* __restrict__ t3,
    const float* __restrict__ t4, signed char* __restrict__ xi,
    signed char* __restrict__ wqkv, signed char* __restrict__ woq,
    const float* __restrict__ scales) {
  const int y = blockIdx.y;
  const float* x = (y == 0) ? t0 : (y == 1) ? t1 : (y == 2) ? t2
                                             : (y == 3) ? t3 : t4;
  const int n4 = (y == 0) ? (1 << 20) : (1 << 18);
  signed char* q = (y == 0) ? xi
                 : (y == 4) ? woq
                            : wqkv + ((size_t)(y - 1) << 20);
  const float s = scales[y];
  const int stride = gridDim.x * 256;
  for (int i = blockIdx.x * 256 + threadIdx.x; i < n4; i += stride) {
    f32x4 v = ((const f32x4*)x)[i];
    int packed = quant1(v[0], s) | (quant1(v[1], s) << 8) |
                 (quant1(v[2], s) << 16) | (quant1(v[3], s) << 24);
    ((int*)q)[i] = packed;
  }
}

// ------------------------------------------------------------------ i8 GEMM
// C[m,n] = sum_k A[m,k]*Bw[n,k], 128x128 tile, 4 waves (2x2), K-step 64B.
// 2-phase pipeline: stage(next) issued before ds_read+MFMA(cur).
template <int EPI>
__global__ __launch_bounds__(256) void gemm_i8_kernel(
    const signed char* __restrict__ A, const signed char* __restrict__ Bw,
    const float* __restrict__ scales, const float* __restrict__ b0,
    const float* __restrict__ b1, const float* __restrict__ b2,
    unsigned short* __restrict__ q_hi, unsigned short* __restrict__ q_lo,
    unsigned short* __restrict__ k_hi, unsigned short* __restrict__ k_lo,
    unsigned short* __restrict__ vt_hi, unsigned short* __restrict__ vt_lo,
    float* __restrict__ out) {
  __shared__ __align__(16) signed char sA[2][8192];
  __shared__ __align__(16) signed char sB[2][8192];
  const int tid = threadIdx.x, w = tid >> 6, l = tid & 63;
  const int NX = EPI ? 8 : 24;
  const int NB = EPI ? 256 : 768;
  const int id = blockIdx.x;
  const int vb = (id & 7) * (NB >> 3) + (id >> 3);
  const int m0 = (vb / NX) * 128, n0 = (vb % NX) * 128;
  const int wm = w >> 1, wn = w & 1;
  const i32x4 zi = {0, 0, 0, 0};
  i32x4 acc[4][4];
#pragma unroll
  for (int r = 0; r < 4; r++)
#pragma unroll
    for (int c = 0; c < 4; c++) acc[r][c] = zi;

#define GSTAGE(bi, kb)                                                       \
  {                                                                          \
    _Pragma("unroll") for (int i = 0; i < 2; i++) {                          \
      int u = i * 4 + w; /* wave-uniform */                                  \
      int slot = u >> 1, row = (u & 1) * 64 + l;                             \
      GLD16(A + (size_t)(m0 + row) * 1024 + (kb) + slot * 16,                \
            sA[bi] + u * 1024);                                              \
      GLD16(Bw + (size_t)(n0 + row) * 1024 + (kb) + slot * 16,               \
            sB[bi] + u * 1024);                                              \
    }                                                                        \
  }

  GSTAGE(0, 0);
  for (int kt = 0; kt < 16; kt++) {
    __syncthreads();  // drains stage(kt) + guarantees buf(kt&1^1) reads done
    if (kt < 15) GSTAGE((kt & 1) ^ 1, (kt + 1) * 64);
    const signed char* pA = sA[kt & 1];
    const signed char* pB = sB[kt & 1];
    i32x4 af[4], bf[4];
#pragma unroll
    for (int r = 0; r < 4; r++)
      af[r] = *(const i32x4*)(pA + ((l >> 4) * 2048 +
                                    (wm * 64 + r * 16 + (l & 15)) * 16));
#pragma unroll
    for (int c = 0; c < 4; c++)
      bf[c] = *(const i32x4*)(pB + ((l >> 4) * 2048 +
                                    (wn * 64 + c * 16 + (l & 15)) * 16));
#pragma unroll
    for (int r = 0; r < 4; r++)
#pragma unroll
      for (int c = 0; c < 4; c++) acc[r][c] = mfma_i8(af[r], bf[c], acc[r][c]);
  }
#undef GSTAGE

  // C/D layout: col = lane&15, row = (lane>>4)*4 + reg   [m89-verified]
  if (EPI == 0) {
    const float sx = scales[0];
#pragma unroll
    for (int c = 0; c < 4; c++) {
      int n = n0 + wn * 64 + c * 16 + (l & 15);
      int sec = n >> 10, o = n & 1023;
      float sy = sx * scales[1 + sec];
      const float* bias = (sec == 0) ? b0 : ((sec == 1) ? b1 : b2);
      float bb = bias[o];
      int h = o >> 6, hd = o & 63;
#pragma unroll
      for (int r = 0; r < 4; r++) {
        int mrow = m0 + wm * 64 + r * 16 + (l >> 4) * 4;
        int b = mrow >> 10, s = mrow & 1023;
        int bh = b * 16 + h;
        float y0 = (float)acc[r][c][0] * sy + bb;
        float y1 = (float)acc[r][c][1] * sy + bb;
        float y2 = (float)acc[r][c][2] * sy + bb;
        float y3 = (float)acc[r][c][3] * sy + bb;
        if (sec == 2) {  // V -> transposed [B,H,HD,S], 4 consecutive s
          size_t base = ((size_t)(bh * 64 + hd)) * 1024 + s;
          ushort4 ph, pl;
          ph.x = f2bf(y0); pl.x = f2bf(y0 - bf2f(ph.x));
          ph.y = f2bf(y1); pl.y = f2bf(y1 - bf2f(ph.y));
          ph.z = f2bf(y2); pl.z = f2bf(y2 - bf2f(ph.z));
          ph.w = f2bf(y3); pl.w = f2bf(y3 - bf2f(ph.w));
          *(ushort4*)(vt_hi + base) = ph;
          *(ushort4*)(vt_lo + base) = pl;
        } else {        // Q/K -> [B,H,S,HD] hi/lo
          unsigned short* hb = (sec == 0) ? q_hi : k_hi;
          unsigned short* lb = (sec == 0) ? q_lo : k_lo;
          size_t base = ((size_t)bh * 1024 + s) * 64 + hd;
          unsigned short t;
          t = f2bf(y0); hb[base]       = t; lb[base]       = f2bf(y0 - bf2f(t));
          t = f2bf(y1); hb[base + 64]  = t; lb[base + 64]  = f2bf(y1 - bf2f(t));
          t = f2bf(y2); hb[base + 128] = t; lb[base + 128] = f2bf(y2 - bf2f(t));
          t = f2bf(y3); hb[base + 192] = t; lb[base + 192] = f2bf(y3 - bf2f(t));
        }
      }
    }
  } else {
    const float sy = scales[5] * scales[4];
#pragma unroll
    for (int c = 0; c < 4; c++) {
      int n = n0 + wn * 64 + c * 16 + (l & 15);
      float bb = b0[n];
#pragma unroll
      for (int r = 0; r < 4; r++) {
        int mrow = m0 + wm * 64 + r * 16 + (l >> 4) * 4;
        out[(size_t)(mrow)     * 1024 + n] = (float)acc[r][c][0] * sy + bb;
        out[(size_t)(mrow + 1) * 1024 + n] = (float)acc[r][c][1] * sy + bb;
        out[(size_t)(mrow + 2) * 1024 + n] = (float)acc[r][c][2] * sy + bb;
        out[(size_t)(mrow + 3) * 1024 + n] = (float)acc[r][c][3] * sy + bb;
      }
    }
  }
}

// --------------------------------------------------------------- attention
// QBLK=128, 4 waves x 32 q-rows (2 sub-blocks of 16). Swapped QK^T
// (mfma(K,Q)): per lane sc[kb][r] = S[key=kt*64+kb*16+g*4+r][q=w*32+qs*16+c].
// P stays in registers and feeds PV A-operand directly (kb-pairs packed into
// one 16x16x32 mfma). K/V double-buffered; counted vmcnt across raw barriers.
__global__ __launch_bounds__(256, 2) void attn_kernel(
    const unsigned short* __restrict__ Qh_, const unsigned short* __restrict__ Ql_,
    const unsigned short* __restrict__ Kh_, const unsigned short* __restrict__ Kl_,
    const unsigned short* __restrict__ Vh_, const unsigned short* __restrict__ Vl_,
    const float* __restrict__ amask, float* __restrict__ attn) {
  __shared__ __align__(16) char smem[65536];
  const int tid = threadIdx.x, w = tid >> 6, l = tid & 63;
  const int g = l >> 4, c = l & 15;
  // XCD swizzle: 8 consecutive bh per XCD -> K/V working set fits one L2.
  const int id = blockIdx.x;              // 0..511
  const int v = (id & 7) * 64 + (id >> 3);
  const int qt = v & 7, bh = v >> 3;
  const int b = bh >> 4, h = bh & 15;
  const int q0 = qt * 128;

  // ---- stage Q: Qh -> smem[0,16K), Ql -> smem[16K,32K) ----
  // chunk u (0..15): LDS u*1024 <- Q[q0 + (u&1)*64 + lane][ (u>>1)*8 ..+7 ]
#pragma unroll
  for (int i = 0; i < 8; i++) {
    int u = i * 4 + w;                   // 0..31 (wave-uniform)
    const unsigned short* src = (u < 16) ? Qh_ : Ql_;
    int uu = u & 15;
    GLD16(src + (size_t)(bh * 1024 + q0 + (uu & 1) * 64 + l) * 64 + (uu >> 1) * 8,
          smem + u * 1024);
  }
  __syncthreads();
  s16x8 aqh[2][2], aql[2][2];            // [qs][ec]
#pragma unroll
  for (int qs = 0; qs < 2; qs++)
#pragma unroll
    for (int ec = 0; ec < 2; ec++) {
      int off = (ec * 4 + g) * 2048 + (w >> 1) * 1024 +
                ((w & 1) * 32 + qs * 16 + c) * 16;
      aqh[qs][ec] = *(const s16x8*)(smem + off);
      aql[qs][ec] = *(const s16x8*)(smem + 16384 + off);
    }
  __syncthreads();  // all waves done reading Q before K/V overwrites region

  const size_t keb = (size_t)(bh * 1024) * 64;   // K row base (ushort)
  const size_t veb = (size_t)(bh * 64 + l) * 1024;

#define ASTAGE(kt_, pb_)                                                     \
  {                                                                          \
    char* base_ = smem + (pb_)*32768;                                        \
    _Pragma("unroll") for (int i = 0; i < 2; i++) {                          \
      int u = i * 4 + w;                                                     \
      GLD16(Kh_ + keb + (size_t)((kt_)*64 + l) * 64 + u * 8, base_ + u * 1024); \
      GLD16(Kl_ + keb + (size_t)((kt_)*64 + l) * 64 + u * 8,                 \
            base_ + 8192 + u * 1024);                                        \
      GLD16(Vh_ + veb + (kt_)*64 + u * 8, base_ + 16384 + u * 1024);         \
      GLD16(Vl_ + veb + (kt_)*64 + u * 8, base_ + 24576 + u * 1024);         \
    }                                                                        \
  }

  const f32x4 zf = {0.f, 0.f, 0.f, 0.f};
  f32x4 o0[4] = {zf, zf, zf, zf}, o1[4] = {zf, zf, zf, zf};
  float mrun0 = -INFINITY, mrun1 = -INFINITY, lrun0 = 0.f, lrun1 = 0.f;

  ASTAGE(0, 0);
  for (int kt = 0; kt < 16; kt++) {
    const int pb = kt & 1;
    if (kt > 0) asm volatile("s_barrier" ::: "memory");  // compute(kt-1) done
    if (kt < 15) {
      ASTAGE(kt + 1, pb ^ 1);
      asm volatile("s_waitcnt vmcnt(8)" ::: "memory");  // kt's batch landed
    } else {
      asm volatile("s_waitcnt vmcnt(0)" ::: "memory");
    }
    asm volatile("s_barrier" ::: "memory");  // buf[pb] published

    const char* pK = smem + pb * 32768;
    const char* pKl = pK + 8192;
    const char* pV = pK + 16384;
    const char* pVl = pK + 24576;

    // mask for this tile (key-indexed; shared by both q-sub-blocks)
    f32x4 msk[4];
#pragma unroll
    for (int kb = 0; kb < 4; kb++) {
      f32x4 mk = *(const f32x4*)(amask + b * 1024 + kt * 64 + kb * 16 + g * 4);
      msk[kb] = mk * 10000.0f - 10000.0f;  // = (1-mk)*-1e4
    }

    // QK^T (swapped): sc[kb][r] = S[key][q], 3-pass hi/lo
    f32x4 sc0[4] = {zf, zf, zf, zf}, sc1[4] = {zf, zf, zf, zf};
#pragma unroll
    for (int ec = 0; ec < 2; ec++)
#pragma unroll
      for (int kb = 0; kb < 4; kb++) {
        int ko = (ec * 4 + g) * 1024 + (kb * 16 + c) * 16;
        s16x8 kh = *(const s16x8*)(pK + ko);
        s16x8 kl = *(const s16x8*)(pKl + ko);
        sc0[kb] = mfma_bf16(kh, aqh[0][ec], sc0[kb]);
        sc0[kb] = mfma_bf16(kh, aql[0][ec], sc0[kb]);
        sc0[kb] = mfma_bf16(kl, aqh[0][ec], sc0[kb]);
        sc1[kb] = mfma_bf16(kh, aqh[1][ec], sc1[kb]);
        sc1[kb] = mfma_bf16(kh, aql[1][ec], sc1[kb]);
        sc1[kb] = mfma_bf16(kl, aqh[1][ec], sc1[kb]);
      }
#pragma unroll
    for (int kb = 0; kb < 4; kb++) {
      sc0[kb] = sc0[kb] * 0.125f + msk[kb];
      sc1[kb] = sc1[kb] * 0.125f + msk[kb];
    }

    // online softmax + pack P into PV A-fragments (all in registers)
    s16x8 pH0[2], pL0[2], pH1[2], pL1[2];
#pragma unroll
    for (int qs = 0; qs < 2; qs++) {
      f32x4* sc = qs ? sc1 : sc0;
      float& mrun = qs ? mrun1 : mrun0;
      float& lrun = qs ? lrun1 : lrun0;
      f32x4* o = qs ? o1 : o0;
      float tm = -INFINITY;
#pragma unroll
      for (int kb = 0; kb < 4; kb++)
#pragma unroll
        for (int r = 0; r < 4; r++) tm = fmaxf(tm, sc[kb][r]);
      tm = fmaxf(tm, __shfl_xor(tm, 16, 64));
      tm = fmaxf(tm, __shfl_xor(tm, 32, 64));
      float mn = fmaxf(mrun, tm);
      float fr = __expf(mrun - mn);
      float ps = 0.f;
#pragma unroll
      for (int kb = 0; kb < 4; kb++)
#pragma unroll
        for (int r = 0; r < 4; r++) {
          float p = __expf(sc[kb][r] - mn);
          sc[kb][r] = p;
          ps += p;
        }
      ps += __shfl_xor(ps, 16, 64);
      ps += __shfl_xor(ps, 32, 64);
      lrun = lrun * fr + ps;
      mrun = mn;
      // rescale o: o-rows are q_local = g*4+reg; fr lives at lanes c==q_local
      f32x4 frq;
#pragma unroll
      for (int r = 0; r < 4; r++) frq[r] = __shfl(fr, g * 4 + r, 64);
#pragma unroll
      for (int db = 0; db < 4; db++) o[db] = o[db] * frq;
      // pack kb-pair fragments: slot j<4 -> kb=2pr, j>=4 -> kb=2pr+1
      s16x8* pH = qs ? pH1 : pH0;
      s16x8* pL = qs ? pL1 : pL0;
#pragma unroll
      for (int pr = 0; pr < 2; pr++) {
        s16x8 ph, pl;
#pragma unroll
        for (int j = 0; j < 4; j++) {
          short hi, lo;
          bfsplit(sc[2 * pr][j], hi, lo);
          ph[j] = hi; pl[j] = lo;
          bfsplit(sc[2 * pr + 1][j], hi, lo);
          ph[4 + j] = hi; pl[4 + j] = lo;
        }
        pH[pr] = ph; pL[pr] = pl;
      }
    }

    // PV: O += P * V. B-fragment: V[key 2pr*16+4g+j | (2pr+1)*16+4g+(j-4)][d]
#pragma unroll
    for (int pr = 0; pr < 2; pr++)
#pragma unroll
      for (int db = 0; db < 4; db++) {
        int vo = (4 * pr + (g >> 1)) * 1024 + (db * 16 + c) * 16 + (g & 1) * 8;
        s16x4 a0 = *(const s16x4*)(pV + vo);
        s16x4 a1 = *(const s16x4*)(pV + vo + 2048);
        s16x4 b0v = *(const s16x4*)(pVl + vo);
        s16x4 b1v = *(const s16x4*)(pVl + vo + 2048);
        s16x8 vh = __builtin_shufflevector(a0, a1, 0, 1, 2, 3, 4, 5, 6, 7);
        s16x8 vl = __builtin_shufflevector(b0v, b1v, 0, 1, 2, 3, 4, 5, 6, 7);
        o0[db] = mfma_bf16(pH0[pr], vh, o0[db]);
        o0[db] = mfma_bf16(pH0[pr], vl, o0[db]);
        o0[db] = mfma_bf16(pL0[pr], vh, o0[db]);
        o1[db] = mfma_bf16(pH1[pr], vh, o1[db]);
        o1[db] = mfma_bf16(pH1[pr], vl, o1[db]);
        o1[db] = mfma_bf16(pL1[pr], vh, o1[db]);
      }
  }
#undef ASTAGE

  // epilogue: divide by lrun, write out
#pragma unroll
  for (int qs = 0; qs < 2; qs++) {
    float lr = qs ? lrun1 : lrun0;
    f32x4* o = qs ? o1 : o0;
    f32x4 li;
#pragma unroll
    for (int r = 0; r < 4; r++) li[r] = 1.0f / __shfl(lr, g * 4 + r, 64);
#pragma unroll
    for (int db = 0; db < 4; db++) {
      f32x4 res = o[db] * li;
#pragma unroll
      for (int r = 0; r < 4; r++) {
        int q = q0 + w * 32 + qs * 16 + g * 4 + r;
        attn[((size_t)(b * 1024 + q)) * 1024 + h * 64 + db * 16 + c] = res[r];
      }
    }
  }
}

// ------------------------------------------------------------------- launch
extern "C" void kernel_launch(void* const* d_in, const int* in_sizes, int n_in,
                              void* d_out, int out_size, void* d_ws,
                              size_t ws_size, hipStream_t stream) {
  const float* hs = (const float*)d_in[0];
  const float* am = (const float*)d_in[1];
  const float* Wq = (const float*)d_in[2];
  const float* bq = (const float*)d_in[3];
  const float* Wk = (const float*)d_in[4];
  const float* bk = (const float*)d_in[5];
  const float* Wv = (const float*)d_in[6];
  const float* bv = (const float*)d_in[7];
  const float* Wo = (const float*)d_in[8];
  const float* bo = (const float*)d_in[9];
  float* out = (float*)d_out;

  char* ws = (char*)d_ws;
  signed char* xi   = (signed char*)(ws);                 // 4 MiB (reused: ai)
  signed char* wqkv = (signed char*)(ws + (4u << 20));    // 3 MiB
  signed char* woq  = (signed char*)(ws + (7u << 20));    // 1 MiB
  unsigned short* qhi  = (unsigned short*)(ws + (8u << 20));
  unsigned short* qlo  = (unsigned short*)(ws + (16u << 20));
  unsigned short* khi  = (unsigned short*)(ws + (24u << 20));
  unsigned short* klo  = (unsigned short*)(ws + (32u << 20));
  unsigned short* vthi = (unsigned short*)(ws + (40u << 20));
  unsigned short* vtlo = (unsigned short*)(ws + (48u << 20));
  float* attn = (float*)(ws + (56u << 20));               // 16 MiB
  signed char* ai = xi;                                   // reuse region
  float* partials = (float*)(ws + (72u << 20));           // 6*256 floats
  float* scales = partials + 6 * 256;                     // 6 floats

  absmax5_kernel<<<dim3(256, 5), 256, 0, stream>>>(hs, Wq, Wk, Wv, Wo,
                                                   partials);
  finalize_kernel<<<5, 256, 0, stream>>>(partials, scales);
  quant5_kernel<<<dim3(256, 5), 256, 0, stream>>>(hs, Wq, Wk, Wv, Wo, xi,
                                                  wqkv, woq, scales);
  gemm_i8_kernel<0><<<768, 256, 0, stream>>>(
      xi, wqkv, scales, bq, bk, bv, qhi, qlo, khi, klo, vthi, vtlo, nullptr);
  attn_kernel<<<512, 256, 0, stream>>>(qhi, qlo, khi, klo, vthi, vtlo, am,
                                       attn);
  absmax_partial<<<256, 256, 0, stream>>>(attn, 1 << 20, partials + 5 * 256);
  finalize_kernel<<<1, 256, 0, stream>>>(partials + 5 * 256, scales + 5);
  quantize_kernel<<<512, 256, 0, stream>>>(attn, ai, scales + 5, 1 << 20);
  gemm_i8_kernel<1><<<256, 256, 0, stream>>>(
      ai, woq, scales, bo, nullptr, nullptr, nullptr, nullptr, nullptr,
      nullptr, nullptr, nullptr, out);
}

// Round 5
// 227.595 us; speedup vs baseline: 1.6261x; 1.0397x over previous
//
#include <hip/hip_runtime.h>
#include <cmath>

// GPT2QuantAttention on MI355X (gfx950).
// B=4 S=1024 D=1024 H=16 HD=64, 8-bit per-tensor symmetric fake-quant.
//
// R5 = R4 resubmitted verbatim (R4 hit GPUAcquisitionTimeout; no data).
// R4 changes vs R3 (attn 78us @ MfmaUtil 26%, Occ 18% (2 blk/CU), 4.2M bank
// conflicts; ~90us of inter-launch gaps across 9 kernels):
//   - attn: KVBLK=32, LDS 32KB double-buffer -> 4 blocks/CU; QBLK=64 ->
//     grid 1024 = 256CU x 4 fully resident. Q direct global->reg (no LDS
//     phase). Fragment-major LDS via per-lane pre-swizzled global_load_lds
//     sources -> all ds_read_b128 lane-linear (conflict-free). V in swizzled
//     V3 global layout so PV B-frags are one 16B load. Defer-max (THR=8).
//   - gemms: counted s_waitcnt vmcnt(4) + raw barriers (no vmcnt(0) drain).
//   - 6 launches (was 9): quant5 inline-reduces partials->scales; attn
//     epilogue computes block absmax; quant_attn inline-reduces -> scale.
//
// ws map (bytes):
//   [0,4M)    xi int8 (reused as ai for output GEMM)
//   [4M,7M)   wqkv int8   [7M,8M) wo int8
//   [8M..56M) Qhi Qlo Khi Klo V3hi V3lo (8M each, bf16)
//     V3 layout: elem(bh,key,d) = (((bh*32+(key>>5))*4+((key>>2)&3))*64+d)*8
//                                 + ((key>>4)&1)*4 + (key&3)
//   [56M,72M) attn fp32 [4096,1024]
//   [72M+..)  partials[5][256], scales[6], apartials[1024]

using f32x4 = __attribute__((ext_vector_type(4))) float;
using i32x4 = __attribute__((ext_vector_type(4))) int;
using s16x8 = __attribute__((ext_vector_type(8))) short;

#define DI __device__ __forceinline__

DI unsigned short f2bf(float x) {  // fp32 -> bf16, round-to-nearest-even
  unsigned u = __float_as_uint(x);
  return (unsigned short)((u + 0x7FFFu + ((u >> 16) & 1u)) >> 16);
}
DI float bf2f(unsigned short h) { return __uint_as_float(((unsigned)h) << 16); }

DI f32x4 mfma_bf16(s16x8 a, s16x8 b, f32x4 c) {
  return __builtin_amdgcn_mfma_f32_16x16x32_bf16(a, b, c, 0, 0, 0);
}
DI i32x4 mfma_i8(i32x4 a, i32x4 b, i32x4 c) {
  return __builtin_amdgcn_mfma_i32_16x16x64_i8(a, b, c, 0, 0, 0);
}

// truncation hi/lo bf16 split (4 ops; pair error ~2^-16 relative)
DI void bfsplit(float x, short& hi, short& lo) {
  unsigned u = __float_as_uint(x);
  hi = (short)(u >> 16);
  float r = x - __uint_as_float(u & 0xFFFF0000u);
  lo = (short)(__float_as_uint(r) >> 16);
}

#define GLD16(gp, sp)                                                        \
  __builtin_amdgcn_global_load_lds(                                          \
      (__attribute__((address_space(1))) void*)(unsigned long long)(gp),     \
      (__attribute__((address_space(3))) void*)(unsigned long long)(sp),     \
      16, 0, 0)

// ---------------------------------------------------------------- reductions
DI float wave_block_max(float m, int tid) {  // 256-thread block max
#pragma unroll
  for (int s = 1; s < 64; s <<= 1) m = fmaxf(m, __shfl_xor(m, s, 64));
  __shared__ float sm[4];
  if ((tid & 63) == 0) sm[tid >> 6] = m;
  __syncthreads();
  return fmaxf(fmaxf(sm[0], sm[1]), fmaxf(sm[2], sm[3]));
}

__global__ __launch_bounds__(256) void absmax5_kernel(
    const float* __restrict__ t0, const float* __restrict__ t1,
    const float* __restrict__ t2, const float* __restrict__ t3,
    const float* __restrict__ t4, float* __restrict__ partials) {
  const int y = blockIdx.y;
  const float* x = (y == 0) ? t0 : (y == 1) ? t1 : (y == 2) ? t2
                                             : (y == 3) ? t3 : t4;
  const int n4 = (y == 0) ? (1 << 20) : (1 << 18);
  float m = 0.f;
  const int stride = gridDim.x * 256;
  for (int i = blockIdx.x * 256 + threadIdx.x; i < n4; i += stride) {
    f32x4 v = ((const f32x4*)x)[i];
    m = fmaxf(m, fmaxf(fmaxf(fabsf(v[0]), fabsf(v[1])),
                       fmaxf(fabsf(v[2]), fabsf(v[3]))));
  }
  m = wave_block_max(m, threadIdx.x);
  if (threadIdx.x == 0) partials[y * 256 + blockIdx.x] = m;
}

DI int quant1(float v, float s) {
  float r = rintf(v / s);  // IEEE div + RNE: matches jnp round-half-even
  r = fminf(fmaxf(r, -127.f), 127.f);
  return ((int)r) & 0xFF;
}

// quantize 5 tensors; each block inline-reduces its tensor's 256 partials to
// the scale (cheap, redundant); block (y,0) publishes scales[y] for the gemms.
__global__ __launch_bounds__(256) void quant5_kernel(
    const float* __restrict__ t0, const float* __restrict__ t1,
    const float* __restrict__ t2, const float* __restrict__ t3,
    const float* __restrict__ t4, signed char* __restrict__ xi,
    signed char* __restrict__ wqkv, signed char* __restrict__ woq,
    const float* __restrict__ partials, float* __restrict__ scales) {
  const int y = blockIdx.y;
  const float* x = (y == 0) ? t0 : (y == 1) ? t1 : (y == 2) ? t2
                                             : (y == 3) ? t3 : t4;
  const int n4 = (y == 0) ? (1 << 20) : (1 << 18);
  signed char* q = (y == 0) ? xi
                 : (y == 4) ? woq
                            : wqkv + ((size_t)(y - 1) << 20);
  float m = wave_block_max(partials[y * 256 + threadIdx.x], threadIdx.x);
  const float s = fmaxf(m / 127.0f, 1e-8f);
  if (blockIdx.x == 0 && threadIdx.x == 0) scales[y] = s;
  const int stride = gridDim.x * 256;
  for (int i = blockIdx.x * 256 + threadIdx.x; i < n4; i += stride) {
    f32x4 v = ((const f32x4*)x)[i];
    int packed = quant1(v[0], s) | (quant1(v[1], s) << 8) |
                 (quant1(v[2], s) << 16) | (quant1(v[3], s) << 24);
    ((int*)q)[i] = packed;
  }
}

// attn absmax inline-reduce (1024 block partials) + quantize attn
__global__ __launch_bounds__(256) void quant_attn_kernel(
    const float* __restrict__ x, signed char* __restrict__ q,
    const float* __restrict__ apart, float* __restrict__ scales) {
  const int tid = threadIdx.x;
  float m = fmaxf(fmaxf(apart[tid], apart[tid + 256]),
                  fmaxf(apart[tid + 512], apart[tid + 768]));
  m = wave_block_max(m, tid);
  const float s = fmaxf(m / 127.0f, 1e-8f);
  if (blockIdx.x == 0 && tid == 0) scales[5] = s;
  const int stride = gridDim.x * 256;
  for (int i = blockIdx.x * 256 + tid; i < (1 << 20); i += stride) {
    f32x4 v = ((const f32x4*)x)[i];
    int packed = quant1(v[0], s) | (quant1(v[1], s) << 8) |
                 (quant1(v[2], s) << 16) | (quant1(v[3], s) << 24);
    ((int*)q)[i] = packed;
  }
}

// ------------------------------------------------------------------ i8 GEMM
// C[m,n] = sum_k A[m,k]*Bw[n,k], 128x128 tile, 4 waves (2x2), K-step 64B.
// Counted vmcnt(4) + raw barriers: stage(kt+1) stays in flight over barrier.
template <int EPI>
__global__ __launch_bounds__(256) void gemm_i8_kernel(
    const signed char* __restrict__ A, const signed char* __restrict__ Bw,
    const float* __restrict__ scales, const float* __restrict__ b0,
    const float* __restrict__ b1, const float* __restrict__ b2,
    unsigned short* __restrict__ q_hi, unsigned short* __restrict__ q_lo,
    unsigned short* __restrict__ k_hi, unsigned short* __restrict__ k_lo,
    unsigned short* __restrict__ v3_hi, unsigned short* __restrict__ v3_lo,
    float* __restrict__ out) {
  __shared__ __align__(16) signed char sA[2][8192];
  __shared__ __align__(16) signed char sB[2][8192];
  const int tid = threadIdx.x, w = tid >> 6, l = tid & 63;
  const int NX = EPI ? 8 : 24;
  const int NB = EPI ? 256 : 768;
  const int id = blockIdx.x;
  const int vb = (id & 7) * (NB >> 3) + (id >> 3);
  const int m0 = (vb / NX) * 128, n0 = (vb % NX) * 128;
  const int wm = w >> 1, wn = w & 1;
  const i32x4 zi = {0, 0, 0, 0};
  i32x4 acc[4][4];
#pragma unroll
  for (int r = 0; r < 4; r++)
#pragma unroll
    for (int c = 0; c < 4; c++) acc[r][c] = zi;

#define GSTAGE(bi, kb)                                                       \
  {                                                                          \
    _Pragma("unroll") for (int i = 0; i < 2; i++) {                          \
      int u = i * 4 + w; /* wave-uniform */                                  \
      int slot = u >> 1, row = (u & 1) * 64 + l;                             \
      GLD16(A + (size_t)(m0 + row) * 1024 + (kb) + slot * 16,                \
            sA[bi] + u * 1024);                                              \
      GLD16(Bw + (size_t)(n0 + row) * 1024 + (kb) + slot * 16,               \
            sB[bi] + u * 1024);                                              \
    }                                                                        \
  }

  GSTAGE(0, 0);
  for (int kt = 0; kt < 16; kt++) {
    const int pb = kt & 1;
    if (kt > 0) asm volatile("s_barrier" ::: "memory");
    if (kt < 15) {
      GSTAGE(pb ^ 1, (kt + 1) * 64);
      asm volatile("s_waitcnt vmcnt(4)" ::: "memory");  // kt's 4 landed
    } else {
      asm volatile("s_waitcnt vmcnt(0)" ::: "memory");
    }
    asm volatile("s_barrier" ::: "memory");
    const signed char* pA = sA[pb];
    const signed char* pB = sB[pb];
    i32x4 af[4], bf[4];
#pragma unroll
    for (int r = 0; r < 4; r++)
      af[r] = *(const i32x4*)(pA + ((l >> 4) * 2048 +
                                    (wm * 64 + r * 16 + (l & 15)) * 16));
#pragma unroll
    for (int c = 0; c < 4; c++)
      bf[c] = *(const i32x4*)(pB + ((l >> 4) * 2048 +
                                    (wn * 64 + c * 16 + (l & 15)) * 16));
#pragma unroll
    for (int r = 0; r < 4; r++)
#pragma unroll
      for (int c = 0; c < 4; c++) acc[r][c] = mfma_i8(af[r], bf[c], acc[r][c]);
  }
#undef GSTAGE

  // C/D layout: col = lane&15, row = (lane>>4)*4 + reg   [m89-verified]
  if (EPI == 0) {
    const float sx = scales[0];
#pragma unroll
    for (int c = 0; c < 4; c++) {
      int n = n0 + wn * 64 + c * 16 + (l & 15);
      int sec = n >> 10, o = n & 1023;
      float sy = sx * scales[1 + sec];
      const float* bias = (sec == 0) ? b0 : ((sec == 1) ? b1 : b2);
      float bb = bias[o];
      int h = o >> 6, hd = o & 63;
#pragma unroll
      for (int r = 0; r < 4; r++) {
        int mrow = m0 + wm * 64 + r * 16 + (l >> 4) * 4;
        int b = mrow >> 10, s = mrow & 1023;
        int bh = b * 16 + h;
        float y0 = (float)acc[r][c][0] * sy + bb;
        float y1 = (float)acc[r][c][1] * sy + bb;
        float y2 = (float)acc[r][c][2] * sy + bb;
        float y3 = (float)acc[r][c][3] * sy + bb;
        if (sec == 2) {  // V -> V3 swizzled layout; 4 consecutive keys s..s+3
          size_t vidx =
              ((((size_t)bh * 32 + (s >> 5)) * 4 + ((s >> 2) & 3)) * 64 + hd) *
                  8 +
              ((s >> 4) & 1) * 4;
          ushort4 ph, pl;
          ph.x = f2bf(y0); pl.x = f2bf(y0 - bf2f(ph.x));
          ph.y = f2bf(y1); pl.y = f2bf(y1 - bf2f(ph.y));
          ph.z = f2bf(y2); pl.z = f2bf(y2 - bf2f(ph.z));
          ph.w = f2bf(y3); pl.w = f2bf(y3 - bf2f(ph.w));
          *(ushort4*)(v3_hi + vidx) = ph;
          *(ushort4*)(v3_lo + vidx) = pl;
        } else {        // Q/K -> [B,H,S,HD] hi/lo
          unsigned short* hb = (sec == 0) ? q_hi : k_hi;
          unsigned short* lb = (sec == 0) ? q_lo : k_lo;
          size_t base = ((size_t)bh * 1024 + s) * 64 + hd;
          unsigned short t;
          t = f2bf(y0); hb[base]       = t; lb[base]       = f2bf(y0 - bf2f(t));
          t = f2bf(y1); hb[base + 64]  = t; lb[base + 64]  = f2bf(y1 - bf2f(t));
          t = f2bf(y2); hb[base + 128] = t; lb[base + 128] = f2bf(y2 - bf2f(t));
          t = f2bf(y3); hb[base + 192] = t; lb[base + 192] = f2bf(y3 - bf2f(t));
        }
      }
    }
  } else {
    const float sy = scales[5] * scales[4];
#pragma unroll
    for (int c = 0; c < 4; c++) {
      int n = n0 + wn * 64 + c * 16 + (l & 15);
      float bb = b0[n];
#pragma unroll
      for (int r = 0; r < 4; r++) {
        int mrow = m0 + wm * 64 + r * 16 + (l >> 4) * 4;
        out[(size_t)(mrow)     * 1024 + n] = (float)acc[r][c][0] * sy + bb;
        out[(size_t)(mrow + 1) * 1024 + n] = (float)acc[r][c][1] * sy + bb;
        out[(size_t)(mrow + 2) * 1024 + n] = (float)acc[r][c][2] * sy + bb;
        out[(size_t)(mrow + 3) * 1024 + n] = (float)acc[r][c][3] * sy + bb;
      }
    }
  }
}

// --------------------------------------------------------------- attention
// grid 1024 (64 bh x 16 q-tiles of 64), 4 waves x 16 q. KVBLK=32, LDS 32KB
// double-buffered, 4 blocks/CU. Fragment-major LDS: every ds_read_b128 is
// lane-linear (conflict-free); global_load_lds sources pre-swizzled per lane.
// Swapped QK^T; P in registers -> PV directly; defer-max THR=8.
__global__ __launch_bounds__(256, 4) void attn_kernel(
    const unsigned short* __restrict__ Qh_, const unsigned short* __restrict__ Ql_,
    const unsigned short* __restrict__ Kh_, const unsigned short* __restrict__ Kl_,
    const unsigned short* __restrict__ V3h_, const unsigned short* __restrict__ V3l_,
    const float* __restrict__ amask, float* __restrict__ attn,
    float* __restrict__ apartials) {
  __shared__ __align__(16) char smem[32768];  // [2][Khi 4K|Klo 4K|Vhi 4K|Vlo 4K]
  const int tid = threadIdx.x, w = tid >> 6, l = tid & 63;
  const int g = l >> 4, c = l & 15;
  const int id = blockIdx.x;               // 0..1023
  const int v = (id & 7) * 128 + (id >> 3);  // 8 bh per XCD
  const int qt = v & 15, bh = v >> 4;
  const int b = bh >> 4, h = bh & 15;
  const int q0 = qt * 64;

  // Q fragments direct from global: lane(g,c) -> Q[q0+w*16+c][ec*32+g*8..+7]
  const size_t qrow = (size_t)(bh * 1024 + q0 + w * 16 + c) * 64;
  s16x8 aqh[2], aql[2];
#pragma unroll
  for (int ec = 0; ec < 2; ec++) {
    aqh[ec] = *(const s16x8*)(Qh_ + qrow + ec * 32 + g * 8);
    aql[ec] = *(const s16x8*)(Ql_ + qrow + ec * 32 + g * 8);
  }

  // stage one 32-key tile into buffer pb_ (16 chunks of 1KB; 4 per wave).
  // K chunk (kb,ec): lane(g,c) <- K[kt*32+kb*16+c][ec*32+g*8]  (16B)
  // V chunk (db):    lane(g,c) <- V3[tile][g*512+db*128+c*8]   (16B)
#define ASTAGE(kt_, pb_)                                                     \
  {                                                                          \
    char* base_ = smem + (pb_)*16384;                                        \
    const size_t krow_ = (size_t)(bh * 1024 + (kt_)*32);                     \
    const size_t v3t_ = ((size_t)bh * 32 + (kt_)) * 2048;                    \
    _Pragma("unroll") for (int i_ = 0; i_ < 4; i_++) {                       \
      int cid_ = i_ * 4 + w; /* wave-uniform */                              \
      if (cid_ < 8) {                                                        \
        int kb_ = (cid_ & 3) >> 1, ec_ = cid_ & 1;                           \
        const unsigned short* src_ = (cid_ < 4) ? Kh_ : Kl_;                 \
        GLD16(src_ + (krow_ + kb_ * 16 + c) * 64 + ec_ * 32 + g * 8,         \
              base_ + cid_ * 1024);                                          \
      } else {                                                               \
        int db_ = cid_ & 3;                                                  \
        const unsigned short* src_ = (cid_ < 12) ? V3h_ : V3l_;              \
        GLD16(src_ + v3t_ + g * 512 + db_ * 128 + c * 8,                     \
              base_ + cid_ * 1024);                                          \
      }                                                                      \
    }                                                                        \
  }

  const f32x4 zf = {0.f, 0.f, 0.f, 0.f};
  f32x4 o[4] = {zf, zf, zf, zf};
  float mrun = -INFINITY, lrun = 0.f;

  ASTAGE(0, 0);
  for (int kt = 0; kt < 32; kt++) {
    const int pb = kt & 1;
    if (kt > 0) asm volatile("s_barrier" ::: "memory");  // buf pb^1 free
    if (kt < 31) {
      ASTAGE(kt + 1, pb ^ 1);
      asm volatile("s_waitcnt vmcnt(4)" ::: "memory");  // tile kt landed
    } else {
      asm volatile("s_waitcnt vmcnt(0)" ::: "memory");
    }
    asm volatile("s_barrier" ::: "memory");  // buf pb published
    const char* pT = smem + pb * 16384;

    // QK^T (swapped): sc[kb][r] = S[key=kt*32+kb*16+g*4+r][q=c]
    f32x4 sc[2] = {zf, zf};
#pragma unroll
    for (int ec = 0; ec < 2; ec++)
#pragma unroll
      for (int kb = 0; kb < 2; kb++) {
        s16x8 kh = *(const s16x8*)(pT + (kb * 2 + ec) * 1024 + l * 16);
        s16x8 kl = *(const s16x8*)(pT + 4096 + (kb * 2 + ec) * 1024 + l * 16);
        sc[kb] = mfma_bf16(kh, aqh[ec], sc[kb]);
        sc[kb] = mfma_bf16(kh, aql[ec], sc[kb]);
        sc[kb] = mfma_bf16(kl, aqh[ec], sc[kb]);
      }
#pragma unroll
    for (int kb = 0; kb < 2; kb++) {
      f32x4 mk = *(const f32x4*)(amask + b * 1024 + kt * 32 + kb * 16 + g * 4);
      sc[kb] = sc[kb] * 0.125f + (mk * 10000.0f - 10000.0f);
    }

    // online softmax (stats per q=c, uniform over g) with defer-max THR=8
    float pm = sc[0][0];
#pragma unroll
    for (int r = 1; r < 4; r++) pm = fmaxf(pm, sc[0][r]);
#pragma unroll
    for (int r = 0; r < 4; r++) pm = fmaxf(pm, sc[1][r]);
    pm = fmaxf(pm, __shfl_xor(pm, 16, 64));
    pm = fmaxf(pm, __shfl_xor(pm, 32, 64));
    if (__any(pm > mrun + 8.0f)) {
      float mn = fmaxf(mrun, pm);
      float fr = __expf(mrun - mn);
      f32x4 frq;
#pragma unroll
      for (int r = 0; r < 4; r++) frq[r] = __shfl(fr, g * 4 + r, 64);
#pragma unroll
      for (int db = 0; db < 4; db++) o[db] *= frq;
      lrun *= fr;
      mrun = mn;
    }
    float ps = 0.f;
#pragma unroll
    for (int kb = 0; kb < 2; kb++)
#pragma unroll
      for (int r = 0; r < 4; r++) {
        float p = __expf(sc[kb][r] - mrun);
        sc[kb][r] = p;
        ps += p;
      }
    ps += __shfl_xor(ps, 16, 64);
    ps += __shfl_xor(ps, 32, 64);
    lrun += ps;

    // pack P: A-slot j<4 -> key g*4+j (kb0), j>=4 -> key 16+g*4+(j-4) (kb1)
    s16x8 ph, pl;
#pragma unroll
    for (int j = 0; j < 4; j++) {
      short hi, lo;
      bfsplit(sc[0][j], hi, lo);
      ph[j] = hi; pl[j] = lo;
      bfsplit(sc[1][j], hi, lo);
      ph[4 + j] = hi; pl[4 + j] = lo;
    }

    // PV: V3 frag is one lane-linear b128 per (db, hi/lo)
#pragma unroll
    for (int db = 0; db < 4; db++) {
      s16x8 vh = *(const s16x8*)(pT + 8192 + db * 1024 + l * 16);
      s16x8 vl = *(const s16x8*)(pT + 12288 + db * 1024 + l * 16);
      o[db] = mfma_bf16(ph, vh, o[db]);
      o[db] = mfma_bf16(ph, vl, o[db]);
      o[db] = mfma_bf16(pl, vh, o[db]);
    }
  }
#undef ASTAGE

  // epilogue: normalize, write, fused block absmax
  f32x4 li;
#pragma unroll
  for (int r = 0; r < 4; r++) li[r] = 1.0f / __shfl(lrun, g * 4 + r, 64);
  float am = 0.f;
#pragma unroll
  for (int db = 0; db < 4; db++) {
    f32x4 res = o[db] * li;
#pragma unroll
    for (int r = 0; r < 4; r++) {
      am = fmaxf(am, fabsf(res[r]));
      int q = q0 + w * 16 + g * 4 + r;
      attn[((size_t)(b * 1024 + q)) * 1024 + h * 64 + db * 16 + c] = res[r];
    }
  }
  __syncthreads();  // LDS free for reduction reuse
#pragma unroll
  for (int s = 1; s < 64; s <<= 1) am = fmaxf(am, __shfl_xor(am, s, 64));
  float* sred = (float*)smem;
  if (l == 0) sred[w] = am;
  __syncthreads();
  if (tid == 0)
    apartials[blockIdx.x] =
        fmaxf(fmaxf(sred[0], sred[1]), fmaxf(sred[2], sred[3]));
}

// ------------------------------------------------------------------- launch
extern "C" void kernel_launch(void* const* d_in, const int* in_sizes, int n_in,
                              void* d_out, int out_size, void* d_ws,
                              size_t ws_size, hipStream_t stream) {
  const float* hs = (const float*)d_in[0];
  const float* am = (const float*)d_in[1];
  const float* Wq = (const float*)d_in[2];
  const float* bq = (const float*)d_in[3];
  const float* Wk = (const float*)d_in[4];
  const float* bk = (const float*)d_in[5];
  const float* Wv = (const float*)d_in[6];
  const float* bv = (const float*)d_in[7];
  const float* Wo = (const float*)d_in[8];
  const float* bo = (const float*)d_in[9];
  float* out = (float*)d_out;

  char* ws = (char*)d_ws;
  signed char* xi   = (signed char*)(ws);                 // 4 MiB (reused: ai)
  signed char* wqkv = (signed char*)(ws + (4u << 20));    // 3 MiB
  signed char* woq  = (signed char*)(ws + (7u << 20));    // 1 MiB
  unsigned short* qhi  = (unsigned short*)(ws + (8u << 20));
  unsigned short* qlo  = (unsigned short*)(ws + (16u << 20));
  unsigned short* khi  = (unsigned short*)(ws + (24u << 20));
  unsigned short* klo  = (unsigned short*)(ws + (32u << 20));
  unsigned short* v3hi = (unsigned short*)(ws + (40u << 20));
  unsigned short* v3lo = (unsigned short*)(ws + (48u << 20));
  float* attn = (float*)(ws + (56u << 20));               // 16 MiB
  signed char* ai = xi;                                   // reuse region
  float* partials = (float*)(ws + (72u << 20));           // 5*256 floats
  float* scales = partials + 5 * 256;                     // 6 floats
  float* apartials = scales + 64;                         // 1024 floats

  absmax5_kernel<<<dim3(256, 5), 256, 0, stream>>>(hs, Wq, Wk, Wv, Wo,
                                                   partials);
  quant5_kernel<<<dim3(256, 5), 256, 0, stream>>>(hs, Wq, Wk, Wv, Wo, xi,
                                                  wqkv, woq, partials, scales);
  gemm_i8_kernel<0><<<768, 256, 0, stream>>>(
      xi, wqkv, scales, bq, bk, bv, qhi, qlo, khi, klo, v3hi, v3lo, nullptr);
  attn_kernel<<<1024, 256, 0, stream>>>(qhi, qlo, khi, klo, v3hi, v3lo, am,
                                        attn, apartials);
  quant_attn_kernel<<<512, 256, 0, stream>>>(attn, ai, apartials, scales);
  gemm_i8_kernel<1><<<256, 256, 0, stream>>>(
      ai, woq, scales, bo, nullptr, nullptr, nullptr, nullptr, nullptr,
      nullptr, nullptr, nullptr, out);
}

// Round 7
// 227.152 us; speedup vs baseline: 1.6293x; 1.0019x over previous
//
#include <hip/hip_runtime.h>
#include <cmath>

// GPT2QuantAttention on MI355X (gfx950).
// B=4 S=1024 D=1024 H=16 HD=64, 8-bit per-tensor symmetric fake-quant.
//
// R7 = R6 + race fix. R6 failed nondeterministically (absmax 0.32 / 468):
// in gemm_o, fa-register global loads (ordinary loads) could be reordered by
// the compiler relative to GLD16 intrinsics, so `s_waitcnt vmcnt(8)` could
// leave un-landed B-tile GLD16s outstanding -> barrier published incomplete
// LDS -> garbage MFMA operands. Fix: compiler-only fences
// (asm volatile("" ::: "memory")) pin LOADB -> WRITEA -> LOADA order so the
// vmem FIFO matches source order and vmcnt(8) provably drains B (oldest).
//
// R6 recap vs R5 (attn 77us, SIMD/LDS-issue bound):
//   - attn: QBLK=128 (32 q/wave), KVBLK=64, 64KB LDS dbuf, grid 512,
//     counted vmcnt(8), conflict-free fragment-major LDS, V3 layout,
//     swapped QK^T, defer-max THR=8, setprio.
//   - gemm_o: fused attn fake-quant (reg-staged) + apartials reduce.
//   - 5 launches.
//
// ws map (bytes):
//   [0,4M)    xi int8
//   [4M,7M)   wqkv int8   [7M,8M) wo int8
//   [8M..56M) Qhi Qlo Khi Klo V3hi V3lo (8M each, bf16)
//     V3 layout: elem(bh,key,d) = (((bh*32+(key>>5))*4+((key>>2)&3))*64+d)*8
//                                 + ((key>>4)&1)*4 + (key&3)
//   [56M,72M) attn fp32 [4096,1024]
//   [72M+..)  partials[5][256], scales[6], apartials[512]

using f32x4 = __attribute__((ext_vector_type(4))) float;
using i32x4 = __attribute__((ext_vector_type(4))) int;
using s16x8 = __attribute__((ext_vector_type(8))) short;

#define DI __device__ __forceinline__
#define FENCE asm volatile("" ::: "memory")

DI unsigned short f2bf(float x) {  // fp32 -> bf16, round-to-nearest-even
  unsigned u = __float_as_uint(x);
  return (unsigned short)((u + 0x7FFFu + ((u >> 16) & 1u)) >> 16);
}
DI float bf2f(unsigned short h) { return __uint_as_float(((unsigned)h) << 16); }

DI f32x4 mfma_bf16(s16x8 a, s16x8 b, f32x4 c) {
  return __builtin_amdgcn_mfma_f32_16x16x32_bf16(a, b, c, 0, 0, 0);
}
DI i32x4 mfma_i8(i32x4 a, i32x4 b, i32x4 c) {
  return __builtin_amdgcn_mfma_i32_16x16x64_i8(a, b, c, 0, 0, 0);
}

// truncation hi/lo bf16 split (4 ops; pair error ~2^-16 relative)
DI void bfsplit(float x, short& hi, short& lo) {
  unsigned u = __float_as_uint(x);
  hi = (short)(u >> 16);
  float r = x - __uint_as_float(u & 0xFFFF0000u);
  lo = (short)(__float_as_uint(r) >> 16);
}

#define GLD16(gp, sp)                                                        \
  __builtin_amdgcn_global_load_lds(                                          \
      (__attribute__((address_space(1))) void*)(unsigned long long)(gp),     \
      (__attribute__((address_space(3))) void*)(unsigned long long)(sp),     \
      16, 0, 0)

// ---------------------------------------------------------------- reductions
DI float wave_block_max(float m, int tid) {  // 256-thread block max
#pragma unroll
  for (int s = 1; s < 64; s <<= 1) m = fmaxf(m, __shfl_xor(m, s, 64));
  __shared__ float sm[4];
  if ((tid & 63) == 0) sm[tid >> 6] = m;
  __syncthreads();
  return fmaxf(fmaxf(sm[0], sm[1]), fmaxf(sm[2], sm[3]));
}

__global__ __launch_bounds__(256) void absmax5_kernel(
    const float* __restrict__ t0, const float* __restrict__ t1,
    const float* __restrict__ t2, const float* __restrict__ t3,
    const float* __restrict__ t4, float* __restrict__ partials) {
  const int y = blockIdx.y;
  const float* x = (y == 0) ? t0 : (y == 1) ? t1 : (y == 2) ? t2
                                             : (y == 3) ? t3 : t4;
  const int n4 = (y == 0) ? (1 << 20) : (1 << 18);
  float m = 0.f;
  const int stride = gridDim.x * 256;
  for (int i = blockIdx.x * 256 + threadIdx.x; i < n4; i += stride) {
    f32x4 v = ((const f32x4*)x)[i];
    m = fmaxf(m, fmaxf(fmaxf(fabsf(v[0]), fabsf(v[1])),
                       fmaxf(fabsf(v[2]), fabsf(v[3]))));
  }
  m = wave_block_max(m, threadIdx.x);
  if (threadIdx.x == 0) partials[y * 256 + blockIdx.x] = m;
}

DI int quant1(float v, float s) {
  float r = rintf(v / s);  // IEEE div + RNE: matches jnp round-half-even
  r = fminf(fmaxf(r, -127.f), 127.f);
  return ((int)r) & 0xFF;
}
DI int quant1m(float v, float inv) {  // reciprocal-mul variant (gemm_o)
  float r = rintf(v * inv);
  r = fminf(fmaxf(r, -127.f), 127.f);
  return ((int)r) & 0xFF;
}

// quantize 5 tensors; each block inline-reduces its tensor's partials.
__global__ __launch_bounds__(256) void quant5_kernel(
    const float* __restrict__ t0, const float* __restrict__ t1,
    const float* __restrict__ t2, const float* __restrict__ t3,
    const float* __restrict__ t4, signed char* __restrict__ xi,
    signed char* __restrict__ wqkv, signed char* __restrict__ woq,
    const float* __restrict__ partials, float* __restrict__ scales) {
  const int y = blockIdx.y;
  const float* x = (y == 0) ? t0 : (y == 1) ? t1 : (y == 2) ? t2
                                             : (y == 3) ? t3 : t4;
  const int n4 = (y == 0) ? (1 << 20) : (1 << 18);
  signed char* q = (y == 0) ? xi
                 : (y == 4) ? woq
                            : wqkv + ((size_t)(y - 1) << 20);
  float m = wave_block_max(partials[y * 256 + threadIdx.x], threadIdx.x);
  const float s = fmaxf(m / 127.0f, 1e-8f);
  if (blockIdx.x == 0 && threadIdx.x == 0) scales[y] = s;
  const int stride = gridDim.x * 256;
  for (int i = blockIdx.x * 256 + threadIdx.x; i < n4; i += stride) {
    f32x4 v = ((const f32x4*)x)[i];
    int packed = quant1(v[0], s) | (quant1(v[1], s) << 8) |
                 (quant1(v[2], s) << 16) | (quant1(v[3], s) << 24);
    ((int*)q)[i] = packed;
  }
}

// ----------------------------------------------------------- QKV i8 GEMM
// C[m,n] = sum_k A[m,k]*Bw[n,k], 128x128 tile, 4 waves (2x2), K-step 64B.
// Counted vmcnt(4) + raw barriers; all staged ops are GLD16 intrinsics
// (relative order preserved by the compiler) -> counting is sound.
__global__ __launch_bounds__(256) void gemm_qkv_kernel(
    const signed char* __restrict__ A, const signed char* __restrict__ Bw,
    const float* __restrict__ scales, const float* __restrict__ b0,
    const float* __restrict__ b1, const float* __restrict__ b2,
    unsigned short* __restrict__ q_hi, unsigned short* __restrict__ q_lo,
    unsigned short* __restrict__ k_hi, unsigned short* __restrict__ k_lo,
    unsigned short* __restrict__ v3_hi, unsigned short* __restrict__ v3_lo) {
  __shared__ __align__(16) signed char sA[2][8192];
  __shared__ __align__(16) signed char sB[2][8192];
  const int tid = threadIdx.x, w = tid >> 6, l = tid & 63;
  const int id = blockIdx.x;
  const int vb = (id & 7) * 96 + (id >> 3);     // 768 blocks, bijective
  const int m0 = (vb / 24) * 128, n0 = (vb % 24) * 128;
  const int wm = w >> 1, wn = w & 1;
  const i32x4 zi = {0, 0, 0, 0};
  i32x4 acc[4][4];
#pragma unroll
  for (int r = 0; r < 4; r++)
#pragma unroll
    for (int c = 0; c < 4; c++) acc[r][c] = zi;

#define GSTAGE(bi, kb)                                                       \
  {                                                                          \
    _Pragma("unroll") for (int i = 0; i < 2; i++) {                          \
      int u = i * 4 + w; /* wave-uniform */                                  \
      int slot = u >> 1, row = (u & 1) * 64 + l;                             \
      GLD16(A + (size_t)(m0 + row) * 1024 + (kb) + slot * 16,                \
            sA[bi] + u * 1024);                                              \
      GLD16(Bw + (size_t)(n0 + row) * 1024 + (kb) + slot * 16,               \
            sB[bi] + u * 1024);                                              \
    }                                                                        \
  }

  GSTAGE(0, 0);
  for (int kt = 0; kt < 16; kt++) {
    const int pb = kt & 1;
    if (kt > 0) asm volatile("s_barrier" ::: "memory");
    if (kt < 15) {
      GSTAGE(pb ^ 1, (kt + 1) * 64);
      FENCE;
      asm volatile("s_waitcnt vmcnt(4)" ::: "memory");  // kt's 4 landed
    } else {
      asm volatile("s_waitcnt vmcnt(0)" ::: "memory");
    }
    asm volatile("s_barrier" ::: "memory");
    const signed char* pA = sA[pb];
    const signed char* pB = sB[pb];
    i32x4 af[4], bf[4];
#pragma unroll
    for (int r = 0; r < 4; r++)
      af[r] = *(const i32x4*)(pA + ((l >> 4) * 2048 +
                                    (wm * 64 + r * 16 + (l & 15)) * 16));
#pragma unroll
    for (int c = 0; c < 4; c++)
      bf[c] = *(const i32x4*)(pB + ((l >> 4) * 2048 +
                                    (wn * 64 + c * 16 + (l & 15)) * 16));
#pragma unroll
    for (int r = 0; r < 4; r++)
#pragma unroll
      for (int c = 0; c < 4; c++) acc[r][c] = mfma_i8(af[r], bf[c], acc[r][c]);
  }
#undef GSTAGE

  // C/D layout: col = lane&15, row = (lane>>4)*4 + reg
  const float sx = scales[0];
#pragma unroll
  for (int c = 0; c < 4; c++) {
    int n = n0 + wn * 64 + c * 16 + (l & 15);
    int sec = n >> 10, o = n & 1023;
    float sy = sx * scales[1 + sec];
    const float* bias = (sec == 0) ? b0 : ((sec == 1) ? b1 : b2);
    float bb = bias[o];
    int h = o >> 6, hd = o & 63;
#pragma unroll
    for (int r = 0; r < 4; r++) {
      int mrow = m0 + wm * 64 + r * 16 + (l >> 4) * 4;
      int b = mrow >> 10, s = mrow & 1023;
      int bh = b * 16 + h;
      float y0 = (float)acc[r][c][0] * sy + bb;
      float y1 = (float)acc[r][c][1] * sy + bb;
      float y2 = (float)acc[r][c][2] * sy + bb;
      float y3 = (float)acc[r][c][3] * sy + bb;
      if (sec == 2) {  // V -> V3 swizzled layout; 4 consecutive keys
        size_t vidx =
            ((((size_t)bh * 32 + (s >> 5)) * 4 + ((s >> 2) & 3)) * 64 + hd) * 8 +
            ((s >> 4) & 1) * 4;
        ushort4 ph, pl;
        ph.x = f2bf(y0); pl.x = f2bf(y0 - bf2f(ph.x));
        ph.y = f2bf(y1); pl.y = f2bf(y1 - bf2f(ph.y));
        ph.z = f2bf(y2); pl.z = f2bf(y2 - bf2f(ph.z));
        ph.w = f2bf(y3); pl.w = f2bf(y3 - bf2f(ph.w));
        *(ushort4*)(v3_hi + vidx) = ph;
        *(ushort4*)(v3_lo + vidx) = pl;
      } else {        // Q/K -> [B,H,S,HD] hi/lo
        unsigned short* hb = (sec == 0) ? q_hi : k_hi;
        unsigned short* lb = (sec == 0) ? q_lo : k_lo;
        size_t base = ((size_t)bh * 1024 + s) * 64 + hd;
        unsigned short t;
        t = f2bf(y0); hb[base]       = t; lb[base]       = f2bf(y0 - bf2f(t));
        t = f2bf(y1); hb[base + 64]  = t; lb[base + 64]  = f2bf(y1 - bf2f(t));
        t = f2bf(y2); hb[base + 128] = t; lb[base + 128] = f2bf(y2 - bf2f(t));
        t = f2bf(y3); hb[base + 192] = t; lb[base + 192] = f2bf(y3 - bf2f(t));
      }
    }
  }
}

// --------------------------------------------------------------- attention
// grid 512 (64 bh x 8 q-tiles of 128), 4 waves x 32 q (2 sub-blocks of 16).
// KVBLK=64, LDS 64KB double-buffered (2 blocks/CU). Each K/V fragment read
// once per wave serves BOTH q-sub-blocks. Fragment-major conflict-free LDS;
// swapped QK^T; P in regs; defer-max THR=8.
__global__ __launch_bounds__(256, 2) void attn_kernel(
    const unsigned short* __restrict__ Qh_, const unsigned short* __restrict__ Ql_,
    const unsigned short* __restrict__ Kh_, const unsigned short* __restrict__ Kl_,
    const unsigned short* __restrict__ V3h_, const unsigned short* __restrict__ V3l_,
    const float* __restrict__ amask, float* __restrict__ attn,
    float* __restrict__ apartials) {
  __shared__ __align__(16) char smem[65536];  // [2][Khi 8K|Klo 8K|Vhi 8K|Vlo 8K]
  const int tid = threadIdx.x, w = tid >> 6, l = tid & 63;
  const int g = l >> 4, c = l & 15;
  const int id = blockIdx.x;                 // 0..511
  const int v = (id & 7) * 64 + (id >> 3);   // 8 bh per XCD
  const int qt = v & 7, bh = v >> 3;
  const int b = bh >> 4, h = bh & 15;
  const int q0 = qt * 128;

  // Q fragments direct from global: lane(g,c), qs sub-block, ec d-half
  s16x8 aqh[2][2], aql[2][2];   // [qs][ec]
#pragma unroll
  for (int qs = 0; qs < 2; qs++) {
    const size_t qrow = (size_t)(bh * 1024 + q0 + w * 32 + qs * 16 + c) * 64;
#pragma unroll
    for (int ec = 0; ec < 2; ec++) {
      aqh[qs][ec] = *(const s16x8*)(Qh_ + qrow + ec * 32 + g * 8);
      aql[qs][ec] = *(const s16x8*)(Ql_ + qrow + ec * 32 + g * 8);
    }
  }
  FENCE;  // keep Q loads (ordinary) ordered before staging GLD16s

  // stage one 64-key tile (32KB = 32 chunks of 1KB; 8 per wave).
  // wave0: Khi, wave1: Klo, wave2: Vhi, wave3: Vlo.
#define ASTAGE(kt_, pb_)                                                     \
  {                                                                          \
    char* dst_ = smem + (pb_)*32768 + w * 8192;                              \
    if (w < 2) {                                                             \
      const unsigned short* src_ = (w == 0) ? Kh_ : Kl_;                     \
      const size_t base_ = (size_t)(bh * 1024 + (kt_)*64 + c) * 64 + g * 8;  \
      _Pragma("unroll") for (int j_ = 0; j_ < 8; j_++)                       \
          GLD16(src_ + base_ + (j_ >> 1) * 1024 + (j_ & 1) * 32,             \
                dst_ + j_ * 1024);                                           \
    } else {                                                                 \
      const unsigned short* src_ = (w == 2) ? V3h_ : V3l_;                   \
      const size_t base_ =                                                   \
          (size_t)(bh * 32 + (kt_)*2) * 2048 + g * 512 + c * 8;              \
      _Pragma("unroll") for (int j_ = 0; j_ < 8; j_++)                       \
          GLD16(src_ + base_ + (j_ >> 2) * 2048 + (j_ & 3) * 128,            \
                dst_ + j_ * 1024);                                           \
    }                                                                        \
  }

  const f32x4 zf = {0.f, 0.f, 0.f, 0.f};
  f32x4 o0[4] = {zf, zf, zf, zf}, o1[4] = {zf, zf, zf, zf};
  float mrun0 = -INFINITY, mrun1 = -INFINITY, lrun0 = 0.f, lrun1 = 0.f;

  ASTAGE(0, 0);
  for (int kt = 0; kt < 16; kt++) {
    const int pb = kt & 1;
    if (kt > 0) asm volatile("s_barrier" ::: "memory");  // buf pb^1 free
    if (kt < 15) {
      ASTAGE(kt + 1, pb ^ 1);
      FENCE;
      asm volatile("s_waitcnt vmcnt(8)" ::: "memory");  // tile kt landed
    } else {
      asm volatile("s_waitcnt vmcnt(0)" ::: "memory");
    }
    asm volatile("s_barrier" ::: "memory");  // buf pb published
    const char* pK = smem + pb * 32768;
    const char* pKl = pK + 8192;
    const char* pV = pK + 16384;
    const char* pVl = pK + 24576;

    // QK^T (swapped): sc{qs}[kb][r] = S[key=kt*64+kb*16+g*4+r][q-col=c]
    f32x4 sc0[4] = {zf, zf, zf, zf}, sc1[4] = {zf, zf, zf, zf};
    __builtin_amdgcn_s_setprio(1);
#pragma unroll
    for (int ec = 0; ec < 2; ec++)
#pragma unroll
      for (int kb = 0; kb < 4; kb++) {
        int ko = (kb * 2 + ec) * 1024 + l * 16;
        s16x8 kh = *(const s16x8*)(pK + ko);
        s16x8 kl = *(const s16x8*)(pKl + ko);
        sc0[kb] = mfma_bf16(kh, aqh[0][ec], sc0[kb]);
        sc0[kb] = mfma_bf16(kh, aql[0][ec], sc0[kb]);
        sc0[kb] = mfma_bf16(kl, aqh[0][ec], sc0[kb]);
        sc1[kb] = mfma_bf16(kh, aqh[1][ec], sc1[kb]);
        sc1[kb] = mfma_bf16(kh, aql[1][ec], sc1[kb]);
        sc1[kb] = mfma_bf16(kl, aqh[1][ec], sc1[kb]);
      }
    __builtin_amdgcn_s_setprio(0);
#pragma unroll
    for (int kb = 0; kb < 4; kb++) {
      f32x4 mk = *(const f32x4*)(amask + b * 1024 + kt * 64 + kb * 16 + g * 4);
      f32x4 msk = mk * 10000.0f - 10000.0f;
      sc0[kb] = sc0[kb] * 0.125f + msk;
      sc1[kb] = sc1[kb] * 0.125f + msk;
    }

    // online softmax per qs (stats per q=c, uniform over g); defer-max THR=8
    s16x8 pH0[2], pL0[2], pH1[2], pL1[2];
#pragma unroll
    for (int qs = 0; qs < 2; qs++) {
      f32x4* sc = qs ? sc1 : sc0;
      float& mrun = qs ? mrun1 : mrun0;
      float& lrun = qs ? lrun1 : lrun0;
      f32x4* o = qs ? o1 : o0;
      float pm = sc[0][0];
#pragma unroll
      for (int r = 1; r < 4; r++) pm = fmaxf(pm, sc[0][r]);
#pragma unroll
      for (int kb = 1; kb < 4; kb++)
#pragma unroll
        for (int r = 0; r < 4; r++) pm = fmaxf(pm, sc[kb][r]);
      pm = fmaxf(pm, __shfl_xor(pm, 16, 64));
      pm = fmaxf(pm, __shfl_xor(pm, 32, 64));
      if (__any(pm > mrun + 8.0f)) {
        float mn = fmaxf(mrun, pm);
        float fr = __expf(mrun - mn);
        f32x4 frq;
#pragma unroll
        for (int r = 0; r < 4; r++) frq[r] = __shfl(fr, g * 4 + r, 64);
#pragma unroll
        for (int db = 0; db < 4; db++) o[db] *= frq;
        lrun *= fr;
        mrun = mn;
      }
      float ps = 0.f;
#pragma unroll
      for (int kb = 0; kb < 4; kb++)
#pragma unroll
        for (int r = 0; r < 4; r++) {
          float p = __expf(sc[kb][r] - mrun);
          sc[kb][r] = p;
          ps += p;
        }
      ps += __shfl_xor(ps, 16, 64);
      ps += __shfl_xor(ps, 32, 64);
      lrun += ps;
      // pack P: frag pr covers keys pr*32..+31 (kb pair 2pr, 2pr+1)
      s16x8* pH = qs ? pH1 : pH0;
      s16x8* pL = qs ? pL1 : pL0;
#pragma unroll
      for (int pr = 0; pr < 2; pr++) {
        s16x8 ph, pl;
#pragma unroll
        for (int j = 0; j < 4; j++) {
          short hi, lo;
          bfsplit(sc[2 * pr][j], hi, lo);
          ph[j] = hi; pl[j] = lo;
          bfsplit(sc[2 * pr + 1][j], hi, lo);
          ph[4 + j] = hi; pl[4 + j] = lo;
        }
        pH[pr] = ph; pL[pr] = pl;
      }
    }

    // PV: V frag (pr,db) read once, serves both qs
    __builtin_amdgcn_s_setprio(1);
#pragma unroll
    for (int pr = 0; pr < 2; pr++)
#pragma unroll
      for (int db = 0; db < 4; db++) {
        int vo = (pr * 4 + db) * 1024 + l * 16;
        s16x8 vh = *(const s16x8*)(pV + vo);
        s16x8 vl = *(const s16x8*)(pVl + vo);
        o0[db] = mfma_bf16(pH0[pr], vh, o0[db]);
        o0[db] = mfma_bf16(pH0[pr], vl, o0[db]);
        o0[db] = mfma_bf16(pL0[pr], vh, o0[db]);
        o1[db] = mfma_bf16(pH1[pr], vh, o1[db]);
        o1[db] = mfma_bf16(pH1[pr], vl, o1[db]);
        o1[db] = mfma_bf16(pL1[pr], vh, o1[db]);
      }
    __builtin_amdgcn_s_setprio(0);
  }
#undef ASTAGE

  // epilogue: normalize, write, fused block absmax
  float am = 0.f;
#pragma unroll
  for (int qs = 0; qs < 2; qs++) {
    float lr = qs ? lrun1 : lrun0;
    f32x4* o = qs ? o1 : o0;
    f32x4 li;
#pragma unroll
    for (int r = 0; r < 4; r++) li[r] = 1.0f / __shfl(lr, g * 4 + r, 64);
#pragma unroll
    for (int db = 0; db < 4; db++) {
      f32x4 res = o[db] * li;
#pragma unroll
      for (int r = 0; r < 4; r++) {
        am = fmaxf(am, fabsf(res[r]));
        int q = q0 + w * 32 + qs * 16 + g * 4 + r;
        attn[((size_t)(b * 1024 + q)) * 1024 + h * 64 + db * 16 + c] = res[r];
      }
    }
  }
  __syncthreads();  // LDS free for reduction reuse
#pragma unroll
  for (int s = 1; s < 64; s <<= 1) am = fmaxf(am, __shfl_xor(am, s, 64));
  float* sred = (float*)smem;
  if (l == 0) sred[w] = am;
  __syncthreads();
  if (tid == 0)
    apartials[blockIdx.x] =
        fmaxf(fmaxf(sred[0], sred[1]), fmaxf(sred[2], sred[3]));
}

// ------------------------------------------------- output GEMM, fused quant
// A = fake-quant(attn) on the fly: fp32 loads -> regs (one iter ahead) ->
// quant+ds_write after barrier. Order pinned with FENCEs so counted vmcnt
// is sound: LOADB (GLD16, oldest) ... LOADA (reg loads, newest) -> vmcnt(8)
// drains B, leaves A in flight.
__global__ __launch_bounds__(256) void gemm_o_kernel(
    const float* __restrict__ attnF, const signed char* __restrict__ Bw,
    const float* __restrict__ scales, const float* __restrict__ apart,
    const float* __restrict__ bo, float* __restrict__ out) {
  __shared__ __align__(16) signed char sA[2][8192];
  __shared__ __align__(16) signed char sB[2][8192];
  const int tid = threadIdx.x, w = tid >> 6, l = tid & 63;
  // attn scale from the 512 block partials
  float mm = fmaxf(apart[tid], apart[tid + 256]);
  mm = wave_block_max(mm, tid);
  const float s5 = fmaxf(mm / 127.0f, 1e-8f);
  const float inv5 = 1.0f / s5;
  const float sy = s5 * scales[4];
  const int id = blockIdx.x;
  const int vb = (id & 7) * 32 + (id >> 3);   // 256 blocks
  const int m0 = (vb >> 3) * 128, n0 = (vb & 7) * 128;
  const int wm = w >> 1, wn = w & 1;
  const i32x4 zi = {0, 0, 0, 0};
  i32x4 acc[4][4];
#pragma unroll
  for (int r = 0; r < 4; r++)
#pragma unroll
    for (int c = 0; c < 4; c++) acc[r][c] = zi;
  f32x4 fa[2][4];

#define LOADA(kb_)                                                           \
  {                                                                          \
    _Pragma("unroll") for (int i = 0; i < 2; i++) {                          \
      int u = i * 4 + w;                                                     \
      int row = (u & 1) * 64 + l;                                            \
      const float* sp_ =                                                     \
          attnF + (size_t)(m0 + row) * 1024 + (kb_) + (u >> 1) * 16;         \
      fa[i][0] = *(const f32x4*)sp_;                                         \
      fa[i][1] = *(const f32x4*)(sp_ + 4);                                   \
      fa[i][2] = *(const f32x4*)(sp_ + 8);                                   \
      fa[i][3] = *(const f32x4*)(sp_ + 12);                                  \
    }                                                                        \
  }
#define WRITEA(bi_)                                                          \
  {                                                                          \
    _Pragma("unroll") for (int i = 0; i < 2; i++) {                          \
      int u = i * 4 + w;                                                     \
      i32x4 pk;                                                              \
      _Pragma("unroll") for (int e = 0; e < 4; e++) {                        \
        f32x4 vv = fa[i][e];                                                 \
        pk[e] = quant1m(vv[0], inv5) | (quant1m(vv[1], inv5) << 8) |         \
                (quant1m(vv[2], inv5) << 16) | (quant1m(vv[3], inv5) << 24); \
      }                                                                      \
      *(i32x4*)(sA[bi_] + u * 1024 + l * 16) = pk;                           \
    }                                                                        \
  }
#define LOADB(bi_, kb_)                                                      \
  {                                                                          \
    _Pragma("unroll") for (int i = 0; i < 2; i++) {                          \
      int u = i * 4 + w;                                                     \
      int slot = u >> 1, row = (u & 1) * 64 + l;                             \
      GLD16(Bw + (size_t)(n0 + row) * 1024 + (kb_) + slot * 16,              \
            sB[bi_] + u * 1024);                                             \
    }                                                                        \
  }

  // prologue: A0 loads -> B0 GLD16 -> quant+write A0 -> A1 loads -> wait B0
  LOADA(0);
  FENCE;
  LOADB(0, 0);
  FENCE;
  WRITEA(0);                                   // implicit wait drains A0 regs
  FENCE;
  LOADA(64);
  FENCE;
  asm volatile("s_waitcnt vmcnt(8)" ::: "memory");   // B0 landed (A1 in flight)
  asm volatile("s_waitcnt lgkmcnt(0)" ::: "memory");
  asm volatile("s_barrier" ::: "memory");
  for (int kt = 0; kt < 16; kt++) {
    const int pb = kt & 1;
    const signed char* pA = sA[pb];
    const signed char* pB = sB[pb];
    i32x4 af[4], bf[4];
#pragma unroll
    for (int r = 0; r < 4; r++)
      af[r] = *(const i32x4*)(pA + ((l >> 4) * 2048 +
                                    (wm * 64 + r * 16 + (l & 15)) * 16));
#pragma unroll
    for (int c = 0; c < 4; c++)
      bf[c] = *(const i32x4*)(pB + ((l >> 4) * 2048 +
                                    (wn * 64 + c * 16 + (l & 15)) * 16));
#pragma unroll
    for (int r = 0; r < 4; r++)
#pragma unroll
      for (int c = 0; c < 4; c++) acc[r][c] = mfma_i8(af[r], bf[c], acc[r][c]);
    if (kt < 15) {
      asm volatile("s_barrier" ::: "memory");  // reads of pb^1 (kt-1) done
      LOADB(pb ^ 1, (kt + 1) * 64);
      FENCE;
      WRITEA(pb ^ 1);                          // implicit wait drains fa regs
      FENCE;
      if (kt < 14) {
        LOADA((kt + 2) * 64);
        FENCE;
        asm volatile("s_waitcnt vmcnt(8)" ::: "memory");  // B landed
      } else {
        asm volatile("s_waitcnt vmcnt(0)" ::: "memory");
      }
      asm volatile("s_waitcnt lgkmcnt(0)" ::: "memory");
      asm volatile("s_barrier" ::: "memory");
    }
  }
#undef LOADA
#undef WRITEA
#undef LOADB

  // epilogue
#pragma unroll
  for (int c = 0; c < 4; c++) {
    int n = n0 + wn * 64 + c * 16 + (l & 15);
    float bb = bo[n];
#pragma unroll
    for (int r = 0; r < 4; r++) {
      int mrow = m0 + wm * 64 + r * 16 + (l >> 4) * 4;
      out[(size_t)(mrow)     * 1024 + n] = (float)acc[r][c][0] * sy + bb;
      out[(size_t)(mrow + 1) * 1024 + n] = (float)acc[r][c][1] * sy + bb;
      out[(size_t)(mrow + 2) * 1024 + n] = (float)acc[r][c][2] * sy + bb;
      out[(size_t)(mrow + 3) * 1024 + n] = (float)acc[r][c][3] * sy + bb;
    }
  }
}

// ------------------------------------------------------------------- launch
extern "C" void kernel_launch(void* const* d_in, const int* in_sizes, int n_in,
                              void* d_out, int out_size, void* d_ws,
                              size_t ws_size, hipStream_t stream) {
  const float* hs = (const float*)d_in[0];
  const float* am = (const float*)d_in[1];
  const float* Wq = (const float*)d_in[2];
  const float* bq = (const float*)d_in[3];
  const float* Wk = (const float*)d_in[4];
  const float* bk = (const float*)d_in[5];
  const float* Wv = (const float*)d_in[6];
  const float* bv = (const float*)d_in[7];
  const float* Wo = (const float*)d_in[8];
  const float* bo = (const float*)d_in[9];
  float* out = (float*)d_out;

  char* ws = (char*)d_ws;
  signed char* xi   = (signed char*)(ws);                 // 4 MiB
  signed char* wqkv = (signed char*)(ws + (4u << 20));    // 3 MiB
  signed char* woq  = (signed char*)(ws + (7u << 20));    // 1 MiB
  unsigned short* qhi  = (unsigned short*)(ws + (8u << 20));
  unsigned short* qlo  = (unsigned short*)(ws + (16u << 20));
  unsigned short* khi  = (unsigned short*)(ws + (24u << 20));
  unsigned short* klo  = (unsigned short*)(ws + (32u << 20));
  unsigned short* v3hi = (unsigned short*)(ws + (40u << 20));
  unsigned short* v3lo = (unsigned short*)(ws + (48u << 20));
  float* attn = (float*)(ws + (56u << 20));               // 16 MiB
  float* partials = (float*)(ws + (72u << 20));           // 5*256 floats
  float* scales = partials + 5 * 256;                     // 6 floats
  float* apartials = scales + 64;                         // 512 floats

  absmax5_kernel<<<dim3(256, 5), 256, 0, stream>>>(hs, Wq, Wk, Wv, Wo,
                                                   partials);
  quant5_kernel<<<dim3(256, 5), 256, 0, stream>>>(hs, Wq, Wk, Wv, Wo, xi,
                                                  wqkv, woq, partials, scales);
  gemm_qkv_kernel<<<768, 256, 0, stream>>>(xi, wqkv, scales, bq, bk, bv, qhi,
                                           qlo, khi, klo, v3hi, v3lo);
  attn_kernel<<<512, 256, 0, stream>>>(qhi, qlo, khi, klo, v3hi, v3lo, am,
                                       attn, apartials);
  gemm_o_kernel<<<256, 256, 0, stream>>>(attn, woq, scales, apartials, bo,
                                         out);
}